// Round 1
// baseline (200.611 us; speedup 1.0000x reference)
//
#include <hip/hip_runtime.h>
#include <math.h>

#define DIMC 192
#define DI   384
#define DS   16
#define LTOK 4096
#define NCH  64
#define CLEN 64
#define NLANE (DI*DS)   // 6144

__device__ __forceinline__ float wave_sum(float v) {
    v += __shfl_xor(v, 1);
    v += __shfl_xor(v, 2);
    v += __shfl_xor(v, 4);
    v += __shfl_xor(v, 8);
    v += __shfl_xor(v, 16);
    v += __shfl_xor(v, 32);
    return v;
}

__device__ __forceinline__ float sigmoidf_(float x) { return 1.f / (1.f + expf(-x)); }
__device__ __forceinline__ float siluf_(float x)    { return x / (1.f + expf(-x)); }

// ---------------- pool: x (192,16,64,64) -> tokens[l=4096][192], mean 4x4 ----------------
__global__ __launch_bounds__(256) void pool_kernel(const float* __restrict__ x,
                                                   float* __restrict__ tokens) {
    int b = blockIdx.x;            // 0..3071 = (c,t)
    int c = b >> 4, t = b & 15;
    __shared__ float pl[4096];     // 64x64 plane
    const float* src = x + (size_t)(c * 16 + t) * 4096;
    int tid = threadIdx.x;
    for (int i = tid; i < 1024; i += 256) {
        float4 v = *(const float4*)(src + i * 4);
        *(float4*)&pl[i * 4] = v;
    }
    __syncthreads();
    int hs = tid >> 4, ws = tid & 15;
    float s = 0.f;
    #pragma unroll
    for (int i = 0; i < 4; ++i) {
        float4 v = *(const float4*)&pl[(hs * 4 + i) * 64 + ws * 4];
        s += v.x + v.y + v.z + v.w;
    }
    s *= 0.0625f;
    int l = t * 256 + hs * 16 + ws;
    tokens[(size_t)l * DIMC + c] = s;
}

// ---------------- ln1: per-token LayerNorm over 192 channels ----------------
__global__ __launch_bounds__(192) void ln1_kernel(const float* __restrict__ tokens,
                                                  const float* __restrict__ g,
                                                  const float* __restrict__ bb,
                                                  float* __restrict__ ytok) {
    int l = blockIdx.x, c = threadIdx.x;
    __shared__ float sb[4];
    float xv = tokens[(size_t)l * DIMC + c];
    float s = wave_sum(xv);
    int wv = c >> 6;
    if ((c & 63) == 0) sb[wv] = s;
    __syncthreads();
    float m = (sb[0] + sb[1] + sb[2]) * (1.f / 192.f);
    float dx = xv - m;
    float s2 = wave_sum(dx * dx);
    __syncthreads();
    if ((c & 63) == 0) sb[wv] = s2;
    __syncthreads();
    float var = (sb[0] + sb[1] + sb[2]) * (1.f / 192.f);
    ytok[(size_t)l * DIMC + c] = dx * rsqrtf(var + 1e-5f) * g[c] + bb[c];
}

// ---------------- generic fp32 GEMM: C[m][n] = sum_k A[m*K+k]*W[n*K+k] ----------------
// tiles 64x64, BK=64; requires M%64==0, N%64==0, K%64==0
__global__ __launch_bounds__(256) void gemm64(const float* __restrict__ A,
                                              const float* __restrict__ W,
                                              float* __restrict__ Cout,
                                              int M, int N, int K) {
    __shared__ float at[64][64];
    __shared__ float bt[64][64];
    int bm = blockIdx.y * 64;
    int bn = blockIdx.x * 64;
    int tid = threadIdx.x;
    int tx = tid & 15, ty = tid >> 4;
    float acc[4][4] = {};
    int row = tid >> 2;
    int colb = (tid & 3) << 4;
    for (int k0 = 0; k0 < K; k0 += 64) {
        const float* sa = A + (size_t)(bm + row) * K + k0 + colb;
        const float* sw = W + (size_t)(bn + row) * K + k0 + colb;
        #pragma unroll
        for (int j = 0; j < 16; j += 4) {
            float4 v = *(const float4*)(sa + j);
            at[colb + j + 0][row] = v.x;
            at[colb + j + 1][row] = v.y;
            at[colb + j + 2][row] = v.z;
            at[colb + j + 3][row] = v.w;
            float4 u = *(const float4*)(sw + j);
            bt[colb + j + 0][row] = u.x;
            bt[colb + j + 1][row] = u.y;
            bt[colb + j + 2][row] = u.z;
            bt[colb + j + 3][row] = u.w;
        }
        __syncthreads();
        #pragma unroll 16
        for (int k = 0; k < 64; ++k) {
            float4 a4 = *(const float4*)&at[k][ty << 2];
            float4 b4 = *(const float4*)&bt[k][tx << 2];
            float av[4] = {a4.x, a4.y, a4.z, a4.w};
            float bv[4] = {b4.x, b4.y, b4.z, b4.w};
            #pragma unroll
            for (int i = 0; i < 4; ++i)
                #pragma unroll
                for (int j2 = 0; j2 < 4; ++j2)
                    acc[i][j2] = fmaf(av[i], bv[j2], acc[i][j2]);
        }
        __syncthreads();
    }
    #pragma unroll
    for (int i = 0; i < 4; ++i) {
        float4 v = make_float4(acc[i][0], acc[i][1], acc[i][2], acc[i][3]);
        *(float4*)&Cout[(size_t)(bm + (ty << 2) + i) * N + bn + (tx << 2)] = v;
    }
}

// ---------------- conv (causal depthwise, k=4) + silu + x_dbl proj + dt ----------------
__global__ __launch_bounds__(384) void conv_proj(const float* __restrict__ xz,
                                                 const float* __restrict__ conv_w,
                                                 const float* __restrict__ conv_b,
                                                 const float* __restrict__ W_xp,
                                                 const float* __restrict__ W_dt,
                                                 const float* __restrict__ b_dt,
                                                 float* __restrict__ xs,
                                                 float* __restrict__ dtb,
                                                 float* __restrict__ Bb,
                                                 float* __restrict__ Cb) {
    int l = blockIdx.x;
    int d = threadIdx.x;           // 0..383
    __shared__ float xs_l[DI];
    __shared__ float xdbl[44];
    float acc = conv_b[d];
    #pragma unroll
    for (int k = 0; k < 4; ++k) {
        int ll = l - 3 + k;
        if (ll >= 0) acc = fmaf(conv_w[d * 4 + k], xz[(size_t)ll * 768 + d], acc);
    }
    float v = siluf_(acc);
    xs_l[d] = v;
    xs[(size_t)l * DI + d] = v;
    __syncthreads();
    int wv = d >> 6, lane = d & 63;
    for (int j = wv; j < 44; j += 6) {
        float p = 0.f;
        #pragma unroll
        for (int r = 0; r < 6; ++r) {
            int dd = lane + r * 64;
            p = fmaf(xs_l[dd], W_xp[(size_t)j * DI + dd], p);
        }
        p = wave_sum(p);
        if (lane == 0) xdbl[j] = p;
    }
    __syncthreads();
    float sdt = b_dt[d];
    #pragma unroll
    for (int r = 0; r < 12; ++r) sdt = fmaf(xdbl[r], W_dt[d * 12 + r], sdt);
    float dtv = (sdt > 20.f) ? sdt : log1pf(expf(sdt));
    dtb[(size_t)l * DI + d] = dtv;
    if (d < DS)            Bb[(size_t)l * DS + d] = xdbl[12 + d];
    else if (d < 2 * DS)   Cb[(size_t)l * DS + (d - DS)] = xdbl[28 + (d - DS)];
}

// ---------------- chunked linear scan: h = a*h + b, a=exp(dt*A), b=dt*B*xs ----------------
__global__ __launch_bounds__(256) void scan_phase1(const float* __restrict__ dtb,
                                                   const float* __restrict__ xs,
                                                   const float* __restrict__ Bm,
                                                   const float* __restrict__ Alog,
                                                   float* __restrict__ chA,
                                                   float* __restrict__ chB) {
    int tid = threadIdx.x;
    int s = tid & 15, dl = tid >> 4;
    int d = blockIdx.x * 16 + dl;
    int c = blockIdx.y;
    float Aval = -expf(Alog[d * DS + s]);
    float h = 0.f, P = 1.f;
    int l0 = c * CLEN;
    for (int i = 0; i < CLEN; ++i) {
        int l = l0 + i;
        float dtv = dtb[(size_t)l * DI + d];
        float a = expf(dtv * Aval);
        float b = dtv * Bm[(size_t)l * DS + s] * xs[(size_t)l * DI + d];
        h = fmaf(a, h, b);
        P *= a;
    }
    int lane = d * DS + s;
    chA[(size_t)c * NLANE + lane] = P;
    chB[(size_t)c * NLANE + lane] = h;
}

__global__ __launch_bounds__(256) void scan_phase2(const float* __restrict__ chA,
                                                   const float* __restrict__ chB,
                                                   float* __restrict__ hst) {
    int lane = blockIdx.x * 256 + threadIdx.x;   // 0..6143
    float h = 0.f;
    for (int c = 0; c < NCH; ++c) {
        float a = chA[(size_t)c * NLANE + lane];
        float b = chB[(size_t)c * NLANE + lane];
        hst[(size_t)c * NLANE + lane] = h;
        h = fmaf(a, h, b);
    }
}

__global__ __launch_bounds__(256) void scan_phase3(const float* __restrict__ dtb,
                                                   const float* __restrict__ xs,
                                                   const float* __restrict__ Bm,
                                                   const float* __restrict__ Cm,
                                                   const float* __restrict__ Alog,
                                                   const float* __restrict__ hst,
                                                   float* __restrict__ ys) {
    int tid = threadIdx.x;
    int s = tid & 15, dl = tid >> 4;
    int d = blockIdx.x * 16 + dl;
    int c = blockIdx.y;
    float Aval = -expf(Alog[d * DS + s]);
    float h = hst[(size_t)c * NLANE + d * DS + s];
    int l0 = c * CLEN;
    for (int i = 0; i < CLEN; ++i) {
        int l = l0 + i;
        float dtv = dtb[(size_t)l * DI + d];
        float a = expf(dtv * Aval);
        float b = dtv * Bm[(size_t)l * DS + s] * xs[(size_t)l * DI + d];
        h = fmaf(a, h, b);
        float yc = h * Cm[(size_t)l * DS + s];
        yc += __shfl_xor(yc, 1);
        yc += __shfl_xor(yc, 2);
        yc += __shfl_xor(yc, 4);
        yc += __shfl_xor(yc, 8);
        if (s == 0) ys[(size_t)l * DI + d] = yc;
    }
}

// ---------------- gate: y = (ys + xs*D) * silu(z) ----------------
__global__ __launch_bounds__(256) void gate_kernel(const float* __restrict__ ys,
                                                   const float* __restrict__ xs,
                                                   const float* __restrict__ Dvec,
                                                   const float* __restrict__ xz,
                                                   float* __restrict__ ybuf) {
    int idx = blockIdx.x * 256 + threadIdx.x;    // < 4096*384
    int l = idx / DI, d = idx - l * DI;
    float z = xz[(size_t)l * 768 + 384 + d];
    ybuf[idx] = (ys[idx] + xs[idx] * Dvec[d]) * siluf_(z);
}

// ---------------- ln2 + residual + transposed store to o5[c][t][sp] ----------------
__global__ __launch_bounds__(192) void ln2_kernel(const float* __restrict__ tokens,
                                                  const float* __restrict__ gout,
                                                  const float* __restrict__ g,
                                                  const float* __restrict__ bb,
                                                  float* __restrict__ o5) {
    int l = blockIdx.x, c = threadIdx.x;
    __shared__ float sb[4];
    float xv = tokens[(size_t)l * DIMC + c] + gout[(size_t)l * DIMC + c];
    float s = wave_sum(xv);
    int wv = c >> 6;
    if ((c & 63) == 0) sb[wv] = s;
    __syncthreads();
    float m = (sb[0] + sb[1] + sb[2]) * (1.f / 192.f);
    float dx = xv - m;
    float s2 = wave_sum(dx * dx);
    __syncthreads();
    if ((c & 63) == 0) sb[wv] = s2;
    __syncthreads();
    float var = (sb[0] + sb[1] + sb[2]) * (1.f / 192.f);
    float val = dx * rsqrtf(var + 1e-5f) * g[c] + bb[c];
    int t = l >> 8, sp = l & 255;
    o5[((size_t)c * 16 + t) * 256 + sp] = val;
}

// ---------------- pooled mean + rfft bins 1..7 + sigmoid -> weight[c] ----------------
__global__ __launch_bounds__(256) void fft_kernel(const float* __restrict__ o5,
                                                  float* __restrict__ wgt) {
    int c = blockIdx.x;
    __shared__ float pooled[16];
    __shared__ float mag[8];
    int tid = threadIdx.x;
    int wv = tid >> 6, lane = tid & 63;
    for (int t = wv * 4; t < wv * 4 + 4; ++t) {
        float s = 0.f;
        #pragma unroll
        for (int r = 0; r < 4; ++r) s += o5[(size_t)c * 4096 + t * 256 + lane + r * 64];
        s = wave_sum(s);
        if (lane == 0) pooled[t] = s * (1.f / 256.f);
    }
    __syncthreads();
    if (tid >= 1 && tid <= 7) {
        int k = tid;
        float re = 0.f, im = 0.f;
        for (int t = 0; t < 16; ++t) {
            float ang = -0.39269908169872414f * (float)(k * t);  // -2*pi/16 * k*t
            re = fmaf(pooled[t], cosf(ang), re);
            im = fmaf(pooled[t], sinf(ang), im);
        }
        mag[k] = sqrtf(re * re + im * im);
    }
    __syncthreads();
    if (tid == 0) {
        float m = 0.f;
        for (int k = 1; k <= 7; ++k) m += mag[k];
        wgt[c] = sigmoidf_(m * (1.f / 7.f));
    }
}

// ---------------- trilinear 4x upsample (H,W) * weight[c] * sigmoid(x) ----------------
__global__ __launch_bounds__(256) void upsample_kernel(const float* __restrict__ o5,
                                                       const float* __restrict__ wgt,
                                                       const float* __restrict__ x,
                                                       float* __restrict__ out) {
    int idx = blockIdx.x * 256 + threadIdx.x;    // < 192*16*64*64
    int w = idx & 63;
    int h = (idx >> 6) & 63;
    int t = (idx >> 12) & 15;
    int c = idx >> 16;
    float sh = h * 0.25f - 0.375f;
    float sw = w * 0.25f - 0.375f;
    int h0 = (int)floorf(sh); float fh = sh - (float)h0;
    int w0 = (int)floorf(sw); float fw = sw - (float)w0;
    int h0c = min(max(h0, 0), 15), h1c = min(max(h0 + 1, 0), 15);
    int w0c = min(max(w0, 0), 15), w1c = min(max(w0 + 1, 0), 15);
    const float* pl = o5 + ((size_t)c * 16 + t) * 256;
    float v00 = pl[h0c * 16 + w0c], v01 = pl[h0c * 16 + w1c];
    float v10 = pl[h1c * 16 + w0c], v11 = pl[h1c * 16 + w1c];
    float v = (v00 * (1.f - fw) + v01 * fw) * (1.f - fh)
            + (v10 * (1.f - fw) + v11 * fw) * fh;
    v *= wgt[c];
    float xv = x[idx];
    out[idx] = v * sigmoidf_(xv);
}

extern "C" void kernel_launch(void* const* d_in, const int* in_sizes, int n_in,
                              void* d_out, int out_size, void* d_ws, size_t ws_size,
                              hipStream_t stream) {
    const float* x      = (const float*)d_in[0];
    const float* ln1_g  = (const float*)d_in[1];
    const float* ln1_b  = (const float*)d_in[2];
    const float* ln2_g  = (const float*)d_in[3];
    const float* ln2_b  = (const float*)d_in[4];
    const float* W_in   = (const float*)d_in[5];
    const float* conv_w = (const float*)d_in[6];
    const float* conv_b = (const float*)d_in[7];
    const float* W_xp   = (const float*)d_in[8];
    const float* W_dt   = (const float*)d_in[9];
    const float* b_dt   = (const float*)d_in[10];
    const float* A_log  = (const float*)d_in[11];
    const float* Dvec   = (const float*)d_in[12];
    const float* W_out  = (const float*)d_in[13];
    float* out = (float*)d_out;

    float* ws = (float*)d_ws;
    float* tokens = ws;  ws += (size_t)LTOK * DIMC;
    float* ytok   = ws;  ws += (size_t)LTOK * DIMC;
    float* xz     = ws;  ws += (size_t)LTOK * 768;
    float* xs     = ws;  ws += (size_t)LTOK * DI;
    float* dtb    = ws;  ws += (size_t)LTOK * DI;
    float* Bb     = ws;  ws += (size_t)LTOK * DS;
    float* Cb     = ws;  ws += (size_t)LTOK * DS;
    float* chA    = ws;  ws += (size_t)NLANE * NCH;
    float* chB    = ws;  ws += (size_t)NLANE * NCH;
    float* hst    = ws;  ws += (size_t)NLANE * NCH;
    float* ysb    = ws;  ws += (size_t)LTOK * DI;
    float* gout   = ws;  ws += (size_t)LTOK * DIMC;
    float* o5     = ws;  ws += (size_t)DIMC * LTOK;
    float* wgt    = ws;  ws += DIMC;
    float* ybuf   = dtb;   // alias: dt dead after scan_phase3

    pool_kernel<<<3072, 256, 0, stream>>>(x, tokens);
    ln1_kernel<<<LTOK, 192, 0, stream>>>(tokens, ln1_g, ln1_b, ytok);
    gemm64<<<dim3(12, 64), 256, 0, stream>>>(ytok, W_in, xz, 4096, 768, 192);
    conv_proj<<<LTOK, 384, 0, stream>>>(xz, conv_w, conv_b, W_xp, W_dt, b_dt, xs, dtb, Bb, Cb);
    scan_phase1<<<dim3(24, 64), 256, 0, stream>>>(dtb, xs, Bb, A_log, chA, chB);
    scan_phase2<<<24, 256, 0, stream>>>(chA, chB, hst);
    scan_phase3<<<dim3(24, 64), 256, 0, stream>>>(dtb, xs, Bb, Cb, A_log, hst, ysb);
    gate_kernel<<<6144, 256, 0, stream>>>(ysb, xs, Dvec, xz, ybuf);
    gemm64<<<dim3(3, 64), 256, 0, stream>>>(ybuf, W_out, gout, 4096, 192, 384);
    ln2_kernel<<<LTOK, 192, 0, stream>>>(tokens, gout, ln2_g, ln2_b, o5);
    fft_kernel<<<192, 256, 0, stream>>>(o5, wgt);
    upsample_kernel<<<49152, 256, 0, stream>>>(o5, wgt, x, out);
}

// Round 2
// 194.456 us; speedup vs baseline: 1.0317x; 1.0317x over previous
//
#include <hip/hip_runtime.h>
#include <math.h>

#define DIMC 192
#define DI   384
#define DS   16
#define LTOK 4096
#define NCH  64
#define CLEN 64
#define NLANE (DI*DS)   // 6144

typedef __attribute__((ext_vector_type(8))) short    bf16x8;
typedef __attribute__((ext_vector_type(8))) unsigned short u16x8;
typedef __attribute__((ext_vector_type(4))) float    f32x4;

__device__ __forceinline__ float wave_sum(float v) {
    v += __shfl_xor(v, 1);
    v += __shfl_xor(v, 2);
    v += __shfl_xor(v, 4);
    v += __shfl_xor(v, 8);
    v += __shfl_xor(v, 16);
    v += __shfl_xor(v, 32);
    return v;
}

__device__ __forceinline__ float sigmoidf_(float x) { return 1.f / (1.f + expf(-x)); }
__device__ __forceinline__ float siluf_(float x)    { return x / (1.f + expf(-x)); }
// round-to-nearest-even float -> bf16 bits
__device__ __forceinline__ unsigned short f2bf(float f) {
    unsigned int u = __float_as_uint(f);
    u += 0x7FFFu + ((u >> 16) & 1u);
    return (unsigned short)(u >> 16);
}
__device__ __forceinline__ float bf2f(unsigned short b) {
    return __uint_as_float(((unsigned int)b) << 16);
}

// ---------------- pool: x (192,16,64,64) -> tokens[l=4096][192], mean 4x4 ----------------
__global__ __launch_bounds__(256) void pool_kernel(const float* __restrict__ x,
                                                   float* __restrict__ tokens) {
    int b = blockIdx.x;            // 0..3071 = (c,t)
    int c = b >> 4, t = b & 15;
    __shared__ float pl[4096];     // 64x64 plane
    const float* src = x + (size_t)(c * 16 + t) * 4096;
    int tid = threadIdx.x;
    for (int i = tid; i < 1024; i += 256) {
        float4 v = *(const float4*)(src + i * 4);
        *(float4*)&pl[i * 4] = v;
    }
    __syncthreads();
    int hs = tid >> 4, ws = tid & 15;
    float s = 0.f;
    #pragma unroll
    for (int i = 0; i < 4; ++i) {
        float4 v = *(const float4*)&pl[(hs * 4 + i) * 64 + ws * 4];
        s += v.x + v.y + v.z + v.w;
    }
    s *= 0.0625f;
    int l = t * 256 + hs * 16 + ws;
    tokens[(size_t)l * DIMC + c] = s;
}

// ---------------- ln1: per-token LayerNorm over 192 channels -> bf16 ----------------
__global__ __launch_bounds__(192) void ln1_kernel(const float* __restrict__ tokens,
                                                  const float* __restrict__ g,
                                                  const float* __restrict__ bb,
                                                  unsigned short* __restrict__ ytok) {
    int l = blockIdx.x, c = threadIdx.x;
    __shared__ float sb[4];
    float xv = tokens[(size_t)l * DIMC + c];
    float s = wave_sum(xv);
    int wv = c >> 6;
    if ((c & 63) == 0) sb[wv] = s;
    __syncthreads();
    float m = (sb[0] + sb[1] + sb[2]) * (1.f / 192.f);
    float dx = xv - m;
    float s2 = wave_sum(dx * dx);
    __syncthreads();
    if ((c & 63) == 0) sb[wv] = s2;
    __syncthreads();
    float var = (sb[0] + sb[1] + sb[2]) * (1.f / 192.f);
    float val = dx * rsqrtf(var + 1e-5f) * g[c] + bb[c];
    ytok[(size_t)l * DIMC + c] = f2bf(val);
}

// ---------------- MFMA GEMM: C[m][n] = sum_k A_bf16[m][k] * W_f32[n][k] ----------------
// BM=BN=64, whole-K LDS panel (K=192 or 384), 4 waves, each 32x32 (2x2 frags of 16x16x32)
template<int K>
__global__ __launch_bounds__(256) void gemm_mfma(const unsigned short* __restrict__ A,
                                                 const float* __restrict__ W,
                                                 float* __restrict__ Cout,
                                                 int N) {
    constexpr int KP = K + 8;      // pad: row stride advances 4 banks -> 2-way (free)
    __shared__ unsigned short As[64 * KP];
    __shared__ unsigned short Bs[64 * KP];
    int bm = blockIdx.y * 64;
    int bn = blockIdx.x * 64;
    int tid = threadIdx.x;
    // stage A (bf16 direct copy), 16B chunks
    for (int c = tid; c < 64 * (K / 8); c += 256) {
        int row = c / (K / 8), col = (c % (K / 8)) * 8;
        u16x8 v = *(const u16x8*)(A + (size_t)(bm + row) * K + col);
        *(u16x8*)&As[row * KP + col] = v;
    }
    // stage W (fp32 -> bf16 convert)
    for (int c = tid; c < 64 * (K / 4); c += 256) {
        int row = c / (K / 4), col = (c % (K / 4)) * 4;
        float4 v = *(const float4*)(W + (size_t)(bn + row) * K + col);
        ushort4 b;
        b.x = f2bf(v.x); b.y = f2bf(v.y); b.z = f2bf(v.z); b.w = f2bf(v.w);
        *(ushort4*)&Bs[row * KP + col] = b;
    }
    __syncthreads();
    int lane = tid & 63, w = tid >> 6;
    int wr = w >> 1, wc = w & 1;
    int r16 = lane & 15, h = lane >> 4;
    f32x4 acc[2][2] = {};
    #pragma unroll
    for (int k0 = 0; k0 < K; k0 += 32) {
        bf16x8 a0 = *(const bf16x8*)&As[(wr * 32 + r16)      * KP + k0 + 8 * h];
        bf16x8 a1 = *(const bf16x8*)&As[(wr * 32 + 16 + r16) * KP + k0 + 8 * h];
        bf16x8 b0 = *(const bf16x8*)&Bs[(wc * 32 + r16)      * KP + k0 + 8 * h];
        bf16x8 b1 = *(const bf16x8*)&Bs[(wc * 32 + 16 + r16) * KP + k0 + 8 * h];
        acc[0][0] = __builtin_amdgcn_mfma_f32_16x16x32_bf16(a0, b0, acc[0][0], 0, 0, 0);
        acc[0][1] = __builtin_amdgcn_mfma_f32_16x16x32_bf16(a0, b1, acc[0][1], 0, 0, 0);
        acc[1][0] = __builtin_amdgcn_mfma_f32_16x16x32_bf16(a1, b0, acc[1][0], 0, 0, 0);
        acc[1][1] = __builtin_amdgcn_mfma_f32_16x16x32_bf16(a1, b1, acc[1][1], 0, 0, 0);
    }
    #pragma unroll
    for (int fm = 0; fm < 2; ++fm)
        #pragma unroll
        for (int fn = 0; fn < 2; ++fn)
            #pragma unroll
            for (int i = 0; i < 4; ++i) {
                int r = bm + wr * 32 + fm * 16 + h * 4 + i;
                int cc = bn + wc * 32 + fn * 16 + r16;
                Cout[(size_t)r * N + cc] = acc[fm][fn][i];
            }
}

// ---------------- conv (causal depthwise, k=4) + silu + x_dbl proj + dt ----------------
__global__ __launch_bounds__(384) void conv_proj(const float* __restrict__ xz,
                                                 const float* __restrict__ conv_w,
                                                 const float* __restrict__ conv_b,
                                                 const float* __restrict__ W_xp,
                                                 const float* __restrict__ W_dt,
                                                 const float* __restrict__ b_dt,
                                                 float* __restrict__ xs,
                                                 float* __restrict__ dtb,
                                                 float* __restrict__ Bb,
                                                 float* __restrict__ Cb) {
    int l = blockIdx.x;
    int d = threadIdx.x;           // 0..383
    __shared__ float xs_l[DI];
    __shared__ float xdbl[44];
    float acc = conv_b[d];
    #pragma unroll
    for (int k = 0; k < 4; ++k) {
        int ll = l - 3 + k;
        if (ll >= 0) acc = fmaf(conv_w[d * 4 + k], xz[(size_t)ll * 768 + d], acc);
    }
    float v = siluf_(acc);
    xs_l[d] = v;
    xs[(size_t)l * DI + d] = v;
    __syncthreads();
    int wv = d >> 6, lane = d & 63;
    for (int j = wv; j < 44; j += 6) {
        float p = 0.f;
        #pragma unroll
        for (int r = 0; r < 6; ++r) {
            int dd = lane + r * 64;
            p = fmaf(xs_l[dd], W_xp[(size_t)j * DI + dd], p);
        }
        p = wave_sum(p);
        if (lane == 0) xdbl[j] = p;
    }
    __syncthreads();
    float sdt = b_dt[d];
    #pragma unroll
    for (int r = 0; r < 12; ++r) sdt = fmaf(xdbl[r], W_dt[d * 12 + r], sdt);
    float dtv = (sdt > 20.f) ? sdt : log1pf(expf(sdt));
    dtb[(size_t)l * DI + d] = dtv;
    if (d < DS)            Bb[(size_t)l * DS + d] = xdbl[12 + d];
    else if (d < 2 * DS)   Cb[(size_t)l * DS + (d - DS)] = xdbl[28 + (d - DS)];
}

// ---------------- chunked linear scan: h = a*h + b, a=exp(dt*A), b=dt*B*xs ----------------
__global__ __launch_bounds__(256) void scan_phase1(const float* __restrict__ dtb,
                                                   const float* __restrict__ xs,
                                                   const float* __restrict__ Bm,
                                                   const float* __restrict__ Alog,
                                                   float* __restrict__ chA,
                                                   float* __restrict__ chB) {
    int tid = threadIdx.x;
    int s = tid & 15, dl = tid >> 4;
    int d = blockIdx.x * 16 + dl;
    int c = blockIdx.y;
    float Aval = -expf(Alog[d * DS + s]);
    float h = 0.f, P = 1.f;
    int l0 = c * CLEN;
    for (int i = 0; i < CLEN; ++i) {
        int l = l0 + i;
        float dtv = dtb[(size_t)l * DI + d];
        float a = expf(dtv * Aval);
        float b = dtv * Bm[(size_t)l * DS + s] * xs[(size_t)l * DI + d];
        h = fmaf(a, h, b);
        P *= a;
    }
    int lane = d * DS + s;
    chA[(size_t)c * NLANE + lane] = P;
    chB[(size_t)c * NLANE + lane] = h;
}

__global__ __launch_bounds__(256) void scan_phase2(const float* __restrict__ chA,
                                                   const float* __restrict__ chB,
                                                   float* __restrict__ hst) {
    int lane = blockIdx.x * 256 + threadIdx.x;   // 0..6143
    float h = 0.f;
    for (int c = 0; c < NCH; ++c) {
        float a = chA[(size_t)c * NLANE + lane];
        float b = chB[(size_t)c * NLANE + lane];
        hst[(size_t)c * NLANE + lane] = h;
        h = fmaf(a, h, b);
    }
}

// phase3 + fused gate: ybuf_bf16[l][d] = (y_scan + xs*D) * silu(z)
__global__ __launch_bounds__(256) void scan_phase3(const float* __restrict__ dtb,
                                                   const float* __restrict__ xs,
                                                   const float* __restrict__ Bm,
                                                   const float* __restrict__ Cm,
                                                   const float* __restrict__ Alog,
                                                   const float* __restrict__ hst,
                                                   const float* __restrict__ xz,
                                                   const float* __restrict__ Dvec,
                                                   unsigned short* __restrict__ ybuf) {
    int tid = threadIdx.x;
    int s = tid & 15, dl = tid >> 4;
    int d = blockIdx.x * 16 + dl;
    int c = blockIdx.y;
    float Aval = -expf(Alog[d * DS + s]);
    float Dv = Dvec[d];
    float h = hst[(size_t)c * NLANE + d * DS + s];
    int l0 = c * CLEN;
    for (int i = 0; i < CLEN; ++i) {
        int l = l0 + i;
        float dtv = dtb[(size_t)l * DI + d];
        float a = expf(dtv * Aval);
        float xv = xs[(size_t)l * DI + d];
        float b = dtv * Bm[(size_t)l * DS + s] * xv;
        h = fmaf(a, h, b);
        float yc = h * Cm[(size_t)l * DS + s];
        yc += __shfl_xor(yc, 1);
        yc += __shfl_xor(yc, 2);
        yc += __shfl_xor(yc, 4);
        yc += __shfl_xor(yc, 8);
        if (s == 0) {
            float z = xz[(size_t)l * 768 + 384 + d];
            float val = (yc + xv * Dv) * siluf_(z);
            ybuf[(size_t)l * DI + d] = f2bf(val);
        }
    }
}

// ---------------- ln2 + residual + transposed store to o5[c][t][sp] ----------------
__global__ __launch_bounds__(192) void ln2_kernel(const float* __restrict__ tokens,
                                                  const float* __restrict__ gout,
                                                  const float* __restrict__ g,
                                                  const float* __restrict__ bb,
                                                  float* __restrict__ o5) {
    int l = blockIdx.x, c = threadIdx.x;
    __shared__ float sb[4];
    float xv = tokens[(size_t)l * DIMC + c] + gout[(size_t)l * DIMC + c];
    float s = wave_sum(xv);
    int wv = c >> 6;
    if ((c & 63) == 0) sb[wv] = s;
    __syncthreads();
    float m = (sb[0] + sb[1] + sb[2]) * (1.f / 192.f);
    float dx = xv - m;
    float s2 = wave_sum(dx * dx);
    __syncthreads();
    if ((c & 63) == 0) sb[wv] = s2;
    __syncthreads();
    float var = (sb[0] + sb[1] + sb[2]) * (1.f / 192.f);
    float val = dx * rsqrtf(var + 1e-5f) * g[c] + bb[c];
    int t = l >> 8, sp = l & 255;
    o5[((size_t)c * 16 + t) * 256 + sp] = val;
}

// ---------------- pooled mean + rfft bins 1..7 + sigmoid -> weight[c] ----------------
__global__ __launch_bounds__(256) void fft_kernel(const float* __restrict__ o5,
                                                  float* __restrict__ wgt) {
    int c = blockIdx.x;
    __shared__ float pooled[16];
    __shared__ float mag[8];
    int tid = threadIdx.x;
    int wv = tid >> 6, lane = tid & 63;
    for (int t = wv * 4; t < wv * 4 + 4; ++t) {
        float s = 0.f;
        #pragma unroll
        for (int r = 0; r < 4; ++r) s += o5[(size_t)c * 4096 + t * 256 + lane + r * 64];
        s = wave_sum(s);
        if (lane == 0) pooled[t] = s * (1.f / 256.f);
    }
    __syncthreads();
    if (tid >= 1 && tid <= 7) {
        int k = tid;
        float re = 0.f, im = 0.f;
        for (int t = 0; t < 16; ++t) {
            float ang = -0.39269908169872414f * (float)(k * t);  // -2*pi/16 * k*t
            re = fmaf(pooled[t], cosf(ang), re);
            im = fmaf(pooled[t], sinf(ang), im);
        }
        mag[k] = sqrtf(re * re + im * im);
    }
    __syncthreads();
    if (tid == 0) {
        float m = 0.f;
        for (int k = 1; k <= 7; ++k) m += mag[k];
        wgt[c] = sigmoidf_(m * (1.f / 7.f));
    }
}

// ---------------- trilinear 4x upsample (H,W) * weight[c] * sigmoid(x) ----------------
__global__ __launch_bounds__(256) void upsample_kernel(const float* __restrict__ o5,
                                                       const float* __restrict__ wgt,
                                                       const float* __restrict__ x,
                                                       float* __restrict__ out) {
    int idx = blockIdx.x * 256 + threadIdx.x;    // < 192*16*64*64
    int w = idx & 63;
    int h = (idx >> 6) & 63;
    int t = (idx >> 12) & 15;
    int c = idx >> 16;
    float sh = h * 0.25f - 0.375f;
    float sw = w * 0.25f - 0.375f;
    int h0 = (int)floorf(sh); float fh = sh - (float)h0;
    int w0 = (int)floorf(sw); float fw = sw - (float)w0;
    int h0c = min(max(h0, 0), 15), h1c = min(max(h0 + 1, 0), 15);
    int w0c = min(max(w0, 0), 15), w1c = min(max(w0 + 1, 0), 15);
    const float* pl = o5 + ((size_t)c * 16 + t) * 256;
    float v00 = pl[h0c * 16 + w0c], v01 = pl[h0c * 16 + w1c];
    float v10 = pl[h1c * 16 + w0c], v11 = pl[h1c * 16 + w1c];
    float v = (v00 * (1.f - fw) + v01 * fw) * (1.f - fh)
            + (v10 * (1.f - fw) + v11 * fw) * fh;
    v *= wgt[c];
    float xv = x[idx];
    out[idx] = v * sigmoidf_(xv);
}

extern "C" void kernel_launch(void* const* d_in, const int* in_sizes, int n_in,
                              void* d_out, int out_size, void* d_ws, size_t ws_size,
                              hipStream_t stream) {
    const float* x      = (const float*)d_in[0];
    const float* ln1_g  = (const float*)d_in[1];
    const float* ln1_b  = (const float*)d_in[2];
    const float* ln2_g  = (const float*)d_in[3];
    const float* ln2_b  = (const float*)d_in[4];
    const float* W_in   = (const float*)d_in[5];
    const float* conv_w = (const float*)d_in[6];
    const float* conv_b = (const float*)d_in[7];
    const float* W_xp   = (const float*)d_in[8];
    const float* W_dt   = (const float*)d_in[9];
    const float* b_dt   = (const float*)d_in[10];
    const float* A_log  = (const float*)d_in[11];
    const float* Dvec   = (const float*)d_in[12];
    const float* W_out  = (const float*)d_in[13];
    float* out = (float*)d_out;

    float* ws = (float*)d_ws;
    float* tokens = ws;  ws += (size_t)LTOK * DIMC;
    float* xz     = ws;  ws += (size_t)LTOK * 768;
    float* xs     = ws;  ws += (size_t)LTOK * DI;
    float* dtb    = ws;  ws += (size_t)LTOK * DI;
    float* Bb     = ws;  ws += (size_t)LTOK * DS;
    float* Cb     = ws;  ws += (size_t)LTOK * DS;
    float* chA    = ws;  ws += (size_t)NLANE * NCH;
    float* chB    = ws;  ws += (size_t)NLANE * NCH;
    float* hst    = ws;  ws += (size_t)NLANE * NCH;
    float* gout   = ws;  ws += (size_t)LTOK * DIMC;
    float* o5     = ws;  ws += (size_t)DIMC * LTOK;
    float* wgt    = ws;  ws += DIMC;
    unsigned short* ytok = (unsigned short*)ws;  ws += (size_t)LTOK * DIMC / 2;
    unsigned short* ybuf = (unsigned short*)ws;  ws += (size_t)LTOK * DI / 2;

    pool_kernel<<<3072, 256, 0, stream>>>(x, tokens);
    ln1_kernel<<<LTOK, 192, 0, stream>>>(tokens, ln1_g, ln1_b, ytok);
    gemm_mfma<192><<<dim3(12, 64), 256, 0, stream>>>(ytok, W_in, xz, 768);
    conv_proj<<<LTOK, 384, 0, stream>>>(xz, conv_w, conv_b, W_xp, W_dt, b_dt, xs, dtb, Bb, Cb);
    scan_phase1<<<dim3(24, 64), 256, 0, stream>>>(dtb, xs, Bb, A_log, chA, chB);
    scan_phase2<<<24, 256, 0, stream>>>(chA, chB, hst);
    scan_phase3<<<dim3(24, 64), 256, 0, stream>>>(dtb, xs, Bb, Cb, A_log, hst, xz, Dvec, ybuf);
    gemm_mfma<384><<<dim3(3, 64), 256, 0, stream>>>(ybuf, W_out, gout, 192);
    ln2_kernel<<<LTOK, 192, 0, stream>>>(tokens, gout, ln2_g, ln2_b, o5);
    fft_kernel<<<192, 256, 0, stream>>>(o5, wgt);
    upsample_kernel<<<49152, 256, 0, stream>>>(o5, wgt, x, out);
}

// Round 3
// 153.825 us; speedup vs baseline: 1.3041x; 1.2641x over previous
//
#include <hip/hip_runtime.h>
#include <math.h>

#define DIMC 192
#define DI   384
#define DS   16
#define LTOK 4096
#define NCH  256
#define CLEN 16
#define NLANE (DI*DS)   // 6144
#define L2E  1.4426950408889634f
#define LN2  0.6931471805599453f

typedef __attribute__((ext_vector_type(8))) short    bf16x8;
typedef __attribute__((ext_vector_type(8))) unsigned short u16x8;
typedef __attribute__((ext_vector_type(4))) float    f32x4;

__device__ __forceinline__ float EXP2(float x) { return __builtin_amdgcn_exp2f(x); }
__device__ __forceinline__ float RCP(float x)  { return __builtin_amdgcn_rcpf(x); }
__device__ __forceinline__ float LOG2(float x) { return __builtin_amdgcn_logf(x); }

__device__ __forceinline__ float wave_sum(float v) {
    v += __shfl_xor(v, 1);
    v += __shfl_xor(v, 2);
    v += __shfl_xor(v, 4);
    v += __shfl_xor(v, 8);
    v += __shfl_xor(v, 16);
    v += __shfl_xor(v, 32);
    return v;
}

__device__ __forceinline__ float sigmoidf_(float x) { return RCP(1.f + EXP2(-x * L2E)); }
__device__ __forceinline__ float siluf_(float x)    { return x * RCP(1.f + EXP2(-x * L2E)); }
// round-to-nearest-even float -> bf16 bits
__device__ __forceinline__ unsigned short f2bf(float f) {
    unsigned int u = __float_as_uint(f);
    u += 0x7FFFu + ((u >> 16) & 1u);
    return (unsigned short)(u >> 16);
}

// ---------------- pool: x (192,16,64,64) -> tokens[l=4096][192], mean 4x4 ----------------
__global__ __launch_bounds__(256) void pool_kernel(const float* __restrict__ x,
                                                   float* __restrict__ tokens) {
    int b = blockIdx.x;            // 0..3071 = (c,t)
    int c = b >> 4, t = b & 15;
    __shared__ float pl[4096];     // 64x64 plane
    const float* src = x + (size_t)(c * 16 + t) * 4096;
    int tid = threadIdx.x;
    for (int i = tid; i < 1024; i += 256) {
        float4 v = *(const float4*)(src + i * 4);
        *(float4*)&pl[i * 4] = v;
    }
    __syncthreads();
    int hs = tid >> 4, ws = tid & 15;
    float s = 0.f;
    #pragma unroll
    for (int i = 0; i < 4; ++i) {
        float4 v = *(const float4*)&pl[(hs * 4 + i) * 64 + ws * 4];
        s += v.x + v.y + v.z + v.w;
    }
    s *= 0.0625f;
    int l = t * 256 + hs * 16 + ws;
    tokens[(size_t)l * DIMC + c] = s;
}

// ---------------- ln1: per-token LayerNorm over 192 channels -> bf16 ----------------
__global__ __launch_bounds__(192) void ln1_kernel(const float* __restrict__ tokens,
                                                  const float* __restrict__ g,
                                                  const float* __restrict__ bb,
                                                  unsigned short* __restrict__ ytok) {
    int l = blockIdx.x, c = threadIdx.x;
    __shared__ float sb[4];
    float xv = tokens[(size_t)l * DIMC + c];
    float s = wave_sum(xv);
    int wv = c >> 6;
    if ((c & 63) == 0) sb[wv] = s;
    __syncthreads();
    float m = (sb[0] + sb[1] + sb[2]) * (1.f / 192.f);
    float dx = xv - m;
    float s2 = wave_sum(dx * dx);
    __syncthreads();
    if ((c & 63) == 0) sb[wv] = s2;
    __syncthreads();
    float var = (sb[0] + sb[1] + sb[2]) * (1.f / 192.f);
    float val = dx * rsqrtf(var + 1e-5f) * g[c] + bb[c];
    ytok[(size_t)l * DIMC + c] = f2bf(val);
}

// ---------------- MFMA GEMM: C[m][n] = sum_k A_bf16[m][k] * W_f32[n][k] ----------------
template<int K>
__global__ __launch_bounds__(256) void gemm_mfma(const unsigned short* __restrict__ A,
                                                 const float* __restrict__ W,
                                                 float* __restrict__ Cout,
                                                 int N) {
    constexpr int KP = K + 8;
    __shared__ unsigned short As[64 * KP];
    __shared__ unsigned short Bs[64 * KP];
    int bm = blockIdx.y * 64;
    int bn = blockIdx.x * 64;
    int tid = threadIdx.x;
    for (int c = tid; c < 64 * (K / 8); c += 256) {
        int row = c / (K / 8), col = (c % (K / 8)) * 8;
        u16x8 v = *(const u16x8*)(A + (size_t)(bm + row) * K + col);
        *(u16x8*)&As[row * KP + col] = v;
    }
    for (int c = tid; c < 64 * (K / 4); c += 256) {
        int row = c / (K / 4), col = (c % (K / 4)) * 4;
        float4 v = *(const float4*)(W + (size_t)(bn + row) * K + col);
        ushort4 b;
        b.x = f2bf(v.x); b.y = f2bf(v.y); b.z = f2bf(v.z); b.w = f2bf(v.w);
        *(ushort4*)&Bs[row * KP + col] = b;
    }
    __syncthreads();
    int lane = tid & 63, w = tid >> 6;
    int wr = w >> 1, wc = w & 1;
    int r16 = lane & 15, h = lane >> 4;
    f32x4 acc[2][2] = {};
    #pragma unroll
    for (int k0 = 0; k0 < K; k0 += 32) {
        bf16x8 a0 = *(const bf16x8*)&As[(wr * 32 + r16)      * KP + k0 + 8 * h];
        bf16x8 a1 = *(const bf16x8*)&As[(wr * 32 + 16 + r16) * KP + k0 + 8 * h];
        bf16x8 b0 = *(const bf16x8*)&Bs[(wc * 32 + r16)      * KP + k0 + 8 * h];
        bf16x8 b1 = *(const bf16x8*)&Bs[(wc * 32 + 16 + r16) * KP + k0 + 8 * h];
        acc[0][0] = __builtin_amdgcn_mfma_f32_16x16x32_bf16(a0, b0, acc[0][0], 0, 0, 0);
        acc[0][1] = __builtin_amdgcn_mfma_f32_16x16x32_bf16(a0, b1, acc[0][1], 0, 0, 0);
        acc[1][0] = __builtin_amdgcn_mfma_f32_16x16x32_bf16(a1, b0, acc[1][0], 0, 0, 0);
        acc[1][1] = __builtin_amdgcn_mfma_f32_16x16x32_bf16(a1, b1, acc[1][1], 0, 0, 0);
    }
    #pragma unroll
    for (int fm = 0; fm < 2; ++fm)
        #pragma unroll
        for (int fn = 0; fn < 2; ++fn)
            #pragma unroll
            for (int i = 0; i < 4; ++i) {
                int r = bm + wr * 32 + fm * 16 + h * 4 + i;
                int cc = bn + wc * 32 + fn * 16 + r16;
                Cout[(size_t)r * N + cc] = acc[fm][fn][i];
            }
}

// ---------------- conv (causal depthwise, k=4) + silu + x_dbl proj + dt ----------------
__global__ __launch_bounds__(384) void conv_proj(const float* __restrict__ xz,
                                                 const float* __restrict__ conv_w,
                                                 const float* __restrict__ conv_b,
                                                 const float* __restrict__ W_xp,
                                                 const float* __restrict__ W_dt,
                                                 const float* __restrict__ b_dt,
                                                 float* __restrict__ xs,
                                                 float* __restrict__ dtb,
                                                 float* __restrict__ Bb,
                                                 float* __restrict__ Cb) {
    int l = blockIdx.x;
    int d = threadIdx.x;           // 0..383
    __shared__ float xs_l[DI];
    __shared__ float xdbl[44];
    float acc = conv_b[d];
    #pragma unroll
    for (int k = 0; k < 4; ++k) {
        int ll = l - 3 + k;
        if (ll >= 0) acc = fmaf(conv_w[d * 4 + k], xz[(size_t)ll * 768 + d], acc);
    }
    float v = siluf_(acc);
    xs_l[d] = v;
    xs[(size_t)l * DI + d] = v;
    __syncthreads();
    int wv = d >> 6, lane = d & 63;
    for (int j = wv; j < 44; j += 6) {
        float p = 0.f;
        #pragma unroll
        for (int r = 0; r < 6; ++r) {
            int dd = lane + r * 64;
            p = fmaf(xs_l[dd], W_xp[(size_t)j * DI + dd], p);
        }
        p = wave_sum(p);
        if (lane == 0) xdbl[j] = p;
    }
    __syncthreads();
    float sdt = b_dt[d];
    #pragma unroll
    for (int r = 0; r < 12; ++r) sdt = fmaf(xdbl[r], W_dt[d * 12 + r], sdt);
    // softplus via exp2/log2
    float dtv = (sdt > 20.f) ? sdt : LOG2(1.f + EXP2(sdt * L2E)) * LN2;
    dtb[(size_t)l * DI + d] = dtv;
    if (d < DS)            Bb[(size_t)l * DS + d] = xdbl[12 + d];
    else if (d < 2 * DS)   Cb[(size_t)l * DS + (d - DS)] = xdbl[28 + (d - DS)];
}

// ---------------- scan: s in registers, thread = one d-channel ----------------
// phase1: per-chunk local scan, summary (prod a, h_local)
__global__ __launch_bounds__(384) void scan1(const float* __restrict__ dtb,
                                             const float* __restrict__ xs,
                                             const float* __restrict__ Bm,
                                             const float* __restrict__ Alog,
                                             float* __restrict__ chA,
                                             float* __restrict__ chB) {
    int d = threadIdx.x, c = blockIdx.x;
    __shared__ float Bs[CLEN * DS];       // 256 floats
    if (d < CLEN * DS) Bs[d] = Bm[(size_t)c * CLEN * DS + d];
    float A2[DS];
    #pragma unroll
    for (int s = 0; s < DS; ++s) A2[s] = -expf(Alog[d * DS + s]) * L2E;
    float h[DS] = {};
    float dts = 0.f;
    __syncthreads();
    #pragma unroll
    for (int i = 0; i < CLEN; ++i) {
        int l = c * CLEN + i;
        float dtv = dtb[(size_t)l * DI + d];
        float xv  = xs[(size_t)l * DI + d];
        float dtx = dtv * xv;
        dts += dtv;
        #pragma unroll
        for (int s = 0; s < DS; ++s) {
            float a = EXP2(dtv * A2[s]);
            h[s] = fmaf(a, h[s], dtx * Bs[i * DS + s]);
        }
    }
    size_t base = (size_t)c * NLANE + d * DS;
    #pragma unroll
    for (int s = 0; s < DS; s += 4) {
        float4 pa, pb;
        pa.x = EXP2(dts * A2[s + 0]); pa.y = EXP2(dts * A2[s + 1]);
        pa.z = EXP2(dts * A2[s + 2]); pa.w = EXP2(dts * A2[s + 3]);
        pb.x = h[s + 0]; pb.y = h[s + 1]; pb.z = h[s + 2]; pb.w = h[s + 3];
        *(float4*)&chA[base + s] = pa;
        *(float4*)&chB[base + s] = pb;
    }
}

// phase2: serial prefix over chunks per (d,s) lane -> exclusive prefix states
__global__ __launch_bounds__(256) void scan2(const float* __restrict__ chA,
                                             const float* __restrict__ chB,
                                             float* __restrict__ hst) {
    int lane = blockIdx.x * 256 + threadIdx.x;   // 0..6143
    float h = 0.f;
    for (int c = 0; c < NCH; ++c) {
        float a = chA[(size_t)c * NLANE + lane];
        float b = chB[(size_t)c * NLANE + lane];
        hst[(size_t)c * NLANE + lane] = h;
        h = fmaf(a, h, b);
    }
}

// phase3: re-scan with prefix, y = sum_s h*C, fused gate -> bf16 ybuf
__global__ __launch_bounds__(384) void scan3(const float* __restrict__ dtb,
                                             const float* __restrict__ xs,
                                             const float* __restrict__ Bm,
                                             const float* __restrict__ Cm,
                                             const float* __restrict__ Alog,
                                             const float* __restrict__ hst,
                                             const float* __restrict__ xz,
                                             const float* __restrict__ Dvec,
                                             unsigned short* __restrict__ ybuf) {
    int d = threadIdx.x, c = blockIdx.x;
    __shared__ float Bs[CLEN * DS];
    __shared__ float Cs[CLEN * DS];
    if (d < CLEN * DS) {
        Bs[d] = Bm[(size_t)c * CLEN * DS + d];
        Cs[d] = Cm[(size_t)c * CLEN * DS + d];
    }
    float A2[DS];
    #pragma unroll
    for (int s = 0; s < DS; ++s) A2[s] = -expf(Alog[d * DS + s]) * L2E;
    float h[DS];
    size_t base = (size_t)c * NLANE + d * DS;
    #pragma unroll
    for (int s = 0; s < DS; s += 4) {
        float4 v = *(const float4*)&hst[base + s];
        h[s] = v.x; h[s + 1] = v.y; h[s + 2] = v.z; h[s + 3] = v.w;
    }
    float Dv = Dvec[d];
    __syncthreads();
    #pragma unroll
    for (int i = 0; i < CLEN; ++i) {
        int l = c * CLEN + i;
        float dtv = dtb[(size_t)l * DI + d];
        float xv  = xs[(size_t)l * DI + d];
        float dtx = dtv * xv;
        float y = 0.f;
        #pragma unroll
        for (int s = 0; s < DS; ++s) {
            float a = EXP2(dtv * A2[s]);
            h[s] = fmaf(a, h[s], dtx * Bs[i * DS + s]);
            y = fmaf(h[s], Cs[i * DS + s], y);
        }
        float z = xz[(size_t)l * 768 + 384 + d];
        float val = (y + xv * Dv) * siluf_(z);
        ybuf[(size_t)l * DI + d] = f2bf(val);
    }
}

// ---------------- ln2 + residual + transposed store to o5[c][t][sp] ----------------
__global__ __launch_bounds__(192) void ln2_kernel(const float* __restrict__ tokens,
                                                  const float* __restrict__ gout,
                                                  const float* __restrict__ g,
                                                  const float* __restrict__ bb,
                                                  float* __restrict__ o5) {
    int l = blockIdx.x, c = threadIdx.x;
    __shared__ float sb[4];
    float xv = tokens[(size_t)l * DIMC + c] + gout[(size_t)l * DIMC + c];
    float s = wave_sum(xv);
    int wv = c >> 6;
    if ((c & 63) == 0) sb[wv] = s;
    __syncthreads();
    float m = (sb[0] + sb[1] + sb[2]) * (1.f / 192.f);
    float dx = xv - m;
    float s2 = wave_sum(dx * dx);
    __syncthreads();
    if ((c & 63) == 0) sb[wv] = s2;
    __syncthreads();
    float var = (sb[0] + sb[1] + sb[2]) * (1.f / 192.f);
    float val = dx * rsqrtf(var + 1e-5f) * g[c] + bb[c];
    int t = l >> 8, sp = l & 255;
    o5[((size_t)c * 16 + t) * 256 + sp] = val;
}

// ---------------- pooled mean + rfft bins 1..7 + sigmoid -> weight[c] ----------------
__global__ __launch_bounds__(256) void fft_kernel(const float* __restrict__ o5,
                                                  float* __restrict__ wgt) {
    int c = blockIdx.x;
    __shared__ float pooled[16];
    __shared__ float mag[8];
    int tid = threadIdx.x;
    int wv = tid >> 6, lane = tid & 63;
    for (int t = wv * 4; t < wv * 4 + 4; ++t) {
        float s = 0.f;
        #pragma unroll
        for (int r = 0; r < 4; ++r) s += o5[(size_t)c * 4096 + t * 256 + lane + r * 64];
        s = wave_sum(s);
        if (lane == 0) pooled[t] = s * (1.f / 256.f);
    }
    __syncthreads();
    if (tid >= 1 && tid <= 7) {
        int k = tid;
        float re = 0.f, im = 0.f;
        for (int t = 0; t < 16; ++t) {
            float ang = -0.39269908169872414f * (float)(k * t);
            re = fmaf(pooled[t], cosf(ang), re);
            im = fmaf(pooled[t], sinf(ang), im);
        }
        mag[k] = sqrtf(re * re + im * im);
    }
    __syncthreads();
    if (tid == 0) {
        float m = 0.f;
        for (int k = 1; k <= 7; ++k) m += mag[k];
        wgt[c] = sigmoidf_(m * (1.f / 7.f));
    }
}

// ---------------- trilinear 4x upsample, 4-wide in w ----------------
__global__ __launch_bounds__(256) void upsample_kernel(const float* __restrict__ o5,
                                                       const float* __restrict__ wgt,
                                                       const float* __restrict__ x,
                                                       float* __restrict__ out) {
    int idx = blockIdx.x * 256 + threadIdx.x;    // < 192*16*64*16
    int k  = idx & 15;            // w-quad index: outputs w = 4k..4k+3
    int h  = (idx >> 4) & 63;
    int t  = (idx >> 10) & 15;
    int c  = idx >> 14;
    float sh = h * 0.25f - 0.375f;
    int h0 = (int)floorf(sh); float fh = sh - (float)h0;
    int h0c = min(max(h0, 0), 15), h1c = min(max(h0 + 1, 0), 15);
    const float* pl = o5 + ((size_t)c * 16 + t) * 256;
    int cm = max(k - 1, 0), cp = min(k + 1, 15);
    float r0m = pl[h0c * 16 + cm], r00 = pl[h0c * 16 + k], r0p = pl[h0c * 16 + cp];
    float r1m = pl[h1c * 16 + cm], r10 = pl[h1c * 16 + k], r1p = pl[h1c * 16 + cp];
    float gh = 1.f - fh;
    float vm = r0m * gh + r1m * fh;
    float v0 = r00 * gh + r10 * fh;
    float vp = r0p * gh + r1p * fh;
    float wc = wgt[c];
    size_t off = (size_t)idx * 4;
    float4 xv = *(const float4*)(x + off);
    float4 o;
    o.x = (vm * 0.375f + v0 * 0.625f) * wc * sigmoidf_(xv.x);
    o.y = (vm * 0.125f + v0 * 0.875f) * wc * sigmoidf_(xv.y);
    o.z = (v0 * 0.875f + vp * 0.125f) * wc * sigmoidf_(xv.z);
    o.w = (v0 * 0.625f + vp * 0.375f) * wc * sigmoidf_(xv.w);
    *(float4*)(out + off) = o;
}

extern "C" void kernel_launch(void* const* d_in, const int* in_sizes, int n_in,
                              void* d_out, int out_size, void* d_ws, size_t ws_size,
                              hipStream_t stream) {
    const float* x      = (const float*)d_in[0];
    const float* ln1_g  = (const float*)d_in[1];
    const float* ln1_b  = (const float*)d_in[2];
    const float* ln2_g  = (const float*)d_in[3];
    const float* ln2_b  = (const float*)d_in[4];
    const float* W_in   = (const float*)d_in[5];
    const float* conv_w = (const float*)d_in[6];
    const float* conv_b = (const float*)d_in[7];
    const float* W_xp   = (const float*)d_in[8];
    const float* W_dt   = (const float*)d_in[9];
    const float* b_dt   = (const float*)d_in[10];
    const float* A_log  = (const float*)d_in[11];
    const float* Dvec   = (const float*)d_in[12];
    const float* W_out  = (const float*)d_in[13];
    float* out = (float*)d_out;

    float* ws = (float*)d_ws;
    float* tokens = ws;  ws += (size_t)LTOK * DIMC;
    float* xz     = ws;  ws += (size_t)LTOK * 768;
    float* xs     = ws;  ws += (size_t)LTOK * DI;
    float* dtb    = ws;  ws += (size_t)LTOK * DI;
    float* Bb     = ws;  ws += (size_t)LTOK * DS;
    float* Cb     = ws;  ws += (size_t)LTOK * DS;
    float* chA    = ws;  ws += (size_t)NLANE * NCH;
    float* chB    = ws;  ws += (size_t)NLANE * NCH;
    float* hst    = ws;  ws += (size_t)NLANE * NCH;
    float* gout   = ws;  ws += (size_t)LTOK * DIMC;
    float* o5     = ws;  ws += (size_t)DIMC * LTOK;
    float* wgt    = ws;  ws += DIMC;
    unsigned short* ytok = (unsigned short*)ws;  ws += (size_t)LTOK * DIMC / 2;
    unsigned short* ybuf = (unsigned short*)ws;  ws += (size_t)LTOK * DI / 2;

    pool_kernel<<<3072, 256, 0, stream>>>(x, tokens);
    ln1_kernel<<<LTOK, 192, 0, stream>>>(tokens, ln1_g, ln1_b, ytok);
    gemm_mfma<192><<<dim3(12, 64), 256, 0, stream>>>(ytok, W_in, xz, 768);
    conv_proj<<<LTOK, 384, 0, stream>>>(xz, conv_w, conv_b, W_xp, W_dt, b_dt, xs, dtb, Bb, Cb);
    scan1<<<NCH, 384, 0, stream>>>(dtb, xs, Bb, A_log, chA, chB);
    scan2<<<NLANE / 256, 256, 0, stream>>>(chA, chB, hst);
    scan3<<<NCH, 384, 0, stream>>>(dtb, xs, Bb, Cb, A_log, hst, xz, Dvec, ybuf);
    gemm_mfma<384><<<dim3(3, 64), 256, 0, stream>>>(ybuf, W_out, gout, 192);
    ln2_kernel<<<LTOK, 192, 0, stream>>>(tokens, gout, ln2_g, ln2_b, o5);
    fft_kernel<<<192, 256, 0, stream>>>(o5, wgt);
    upsample_kernel<<<12288, 256, 0, stream>>>(o5, wgt, x, out);
}

// Round 4
// 141.602 us; speedup vs baseline: 1.4167x; 1.0863x over previous
//
#include <hip/hip_runtime.h>
#include <math.h>

#define DIMC 192
#define DI   384
#define DS   16
#define LTOK 4096
#define NCH  128
#define CLEN 32
#define NLANE (DI*DS)   // 6144
#define L2E  1.4426950408889634f
#define LN2  0.6931471805599453f

typedef __attribute__((ext_vector_type(8))) short    bf16x8;
typedef __attribute__((ext_vector_type(8))) unsigned short u16x8;
typedef __attribute__((ext_vector_type(4))) float    f32x4;

__device__ __forceinline__ float EXP2(float x) { return __builtin_amdgcn_exp2f(x); }
__device__ __forceinline__ float RCP(float x)  { return __builtin_amdgcn_rcpf(x); }
__device__ __forceinline__ float LOG2(float x) { return __builtin_amdgcn_logf(x); }

__device__ __forceinline__ float wave_sum(float v) {
    v += __shfl_xor(v, 1);
    v += __shfl_xor(v, 2);
    v += __shfl_xor(v, 4);
    v += __shfl_xor(v, 8);
    v += __shfl_xor(v, 16);
    v += __shfl_xor(v, 32);
    return v;
}

__device__ __forceinline__ float sigmoidf_(float x) { return RCP(1.f + EXP2(-x * L2E)); }
__device__ __forceinline__ float siluf_(float x)    { return x * RCP(1.f + EXP2(-x * L2E)); }
__device__ __forceinline__ unsigned short f2bf(float f) {
    unsigned int u = __float_as_uint(f);
    u += 0x7FFFu + ((u >> 16) & 1u);
    return (unsigned short)(u >> 16);
}
__device__ __forceinline__ float bf2f(unsigned short b) {
    return __uint_as_float(((unsigned int)b) << 16);
}

// ---------------- fused pool (1,4,4 mean) + ln1 -> tokens f32, ytok bf16 ----------------
// block = (t, hs): 16x16 = 256 blocks; 256 threads = 16 groups x 16 lanes
__global__ __launch_bounds__(256) void poolln_kernel(const float* __restrict__ x,
                                                     const float* __restrict__ g,
                                                     const float* __restrict__ bb,
                                                     float* __restrict__ tokens,
                                                     unsigned short* __restrict__ ytok) {
    int blk = blockIdx.x;
    int t = blk >> 4, hs = blk & 15;
    int tid = threadIdx.x;
    int grp = tid >> 4, ws = tid & 15;
    __shared__ float P[16][200];      // [token ws][channel c], pad 200 vs 192
    __shared__ float ms[16], rs[16];
    #pragma unroll
    for (int k = 0; k < 12; ++k) {
        int c = grp + (k << 4);
        const float* base = x + ((size_t)(c * 16 + t) * 64 + hs * 4) * 64 + ws * 4;
        float s = 0.f;
        #pragma unroll
        for (int i = 0; i < 4; ++i) {
            float4 v = *(const float4*)(base + i * 64);
            s += v.x + v.y + v.z + v.w;
        }
        P[ws][c] = s * 0.0625f;
    }
    __syncthreads();
    // LN stats: thread (tk=grp, j=ws) reduces 12 channels, then 16-lane shfl tree
    float s1 = 0.f, s2 = 0.f;
    #pragma unroll
    for (int k = 0; k < 12; ++k) {
        float v = P[grp][ws + 16 * k];
        s1 += v; s2 += v * v;
    }
    s1 += __shfl_xor(s1, 1); s2 += __shfl_xor(s2, 1);
    s1 += __shfl_xor(s1, 2); s2 += __shfl_xor(s2, 2);
    s1 += __shfl_xor(s1, 4); s2 += __shfl_xor(s2, 4);
    s1 += __shfl_xor(s1, 8); s2 += __shfl_xor(s2, 8);
    if (ws == 0) {
        float m = s1 * (1.f / 192.f);
        ms[grp] = m;
        rs[grp] = rsqrtf(s2 * (1.f / 192.f) - m * m + 1e-5f);
    }
    __syncthreads();
    int l0 = t * 256 + hs * 16;
    for (int e = tid; e < 16 * 192; e += 256) {
        int w2 = e / 192, c = e - w2 * 192;
        float v = P[w2][c];
        float val = (v - ms[w2]) * rs[w2] * g[c] + bb[c];
        tokens[(size_t)(l0 + w2) * DIMC + c] = v;
        ytok[(size_t)(l0 + w2) * DIMC + c] = f2bf(val);
    }
}

// ---------------- MFMA GEMM: C[m][n] = sum_k A_bf16[m][k] * W_f32[n][k] ----------------
template<int K>
__global__ __launch_bounds__(256) void gemm_mfma(const unsigned short* __restrict__ A,
                                                 const float* __restrict__ W,
                                                 float* __restrict__ Cout,
                                                 int N) {
    constexpr int KP = K + 8;
    __shared__ unsigned short As[64 * KP];
    __shared__ unsigned short Bs[64 * KP];
    int bm = blockIdx.y * 64;
    int bn = blockIdx.x * 64;
    int tid = threadIdx.x;
    for (int c = tid; c < 64 * (K / 8); c += 256) {
        int row = c / (K / 8), col = (c % (K / 8)) * 8;
        u16x8 v = *(const u16x8*)(A + (size_t)(bm + row) * K + col);
        *(u16x8*)&As[row * KP + col] = v;
    }
    for (int c = tid; c < 64 * (K / 4); c += 256) {
        int row = c / (K / 4), col = (c % (K / 4)) * 4;
        float4 v = *(const float4*)(W + (size_t)(bn + row) * K + col);
        ushort4 b;
        b.x = f2bf(v.x); b.y = f2bf(v.y); b.z = f2bf(v.z); b.w = f2bf(v.w);
        *(ushort4*)&Bs[row * KP + col] = b;
    }
    __syncthreads();
    int lane = tid & 63, w = tid >> 6;
    int wr = w >> 1, wc = w & 1;
    int r16 = lane & 15, h = lane >> 4;
    f32x4 acc[2][2] = {};
    #pragma unroll
    for (int k0 = 0; k0 < K; k0 += 32) {
        bf16x8 a0 = *(const bf16x8*)&As[(wr * 32 + r16)      * KP + k0 + 8 * h];
        bf16x8 a1 = *(const bf16x8*)&As[(wr * 32 + 16 + r16) * KP + k0 + 8 * h];
        bf16x8 b0 = *(const bf16x8*)&Bs[(wc * 32 + r16)      * KP + k0 + 8 * h];
        bf16x8 b1 = *(const bf16x8*)&Bs[(wc * 32 + 16 + r16) * KP + k0 + 8 * h];
        acc[0][0] = __builtin_amdgcn_mfma_f32_16x16x32_bf16(a0, b0, acc[0][0], 0, 0, 0);
        acc[0][1] = __builtin_amdgcn_mfma_f32_16x16x32_bf16(a0, b1, acc[0][1], 0, 0, 0);
        acc[1][0] = __builtin_amdgcn_mfma_f32_16x16x32_bf16(a1, b0, acc[1][0], 0, 0, 0);
        acc[1][1] = __builtin_amdgcn_mfma_f32_16x16x32_bf16(a1, b1, acc[1][1], 0, 0, 0);
    }
    #pragma unroll
    for (int fm = 0; fm < 2; ++fm)
        #pragma unroll
        for (int fn = 0; fn < 2; ++fn)
            #pragma unroll
            for (int i = 0; i < 4; ++i) {
                int r = bm + wr * 32 + fm * 16 + h * 4 + i;
                int cc = bn + wc * 32 + fn * 16 + r16;
                Cout[(size_t)r * N + cc] = acc[fm][fn][i];
            }
}

// ---------------- conv (causal depthwise, k=4) + silu + x_dbl proj + dt ----------------
__global__ __launch_bounds__(384) void conv_proj(const float* __restrict__ xz,
                                                 const float* __restrict__ conv_w,
                                                 const float* __restrict__ conv_b,
                                                 const float* __restrict__ W_xp,
                                                 const float* __restrict__ W_dt,
                                                 const float* __restrict__ b_dt,
                                                 unsigned short* __restrict__ xsb,
                                                 float* __restrict__ dtb,
                                                 float* __restrict__ Bb,
                                                 float* __restrict__ Cb) {
    int l = blockIdx.x;
    int d = threadIdx.x;           // 0..383
    __shared__ float xs_l[DI];
    __shared__ float xdbl[44];
    float acc = conv_b[d];
    #pragma unroll
    for (int k = 0; k < 4; ++k) {
        int ll = l - 3 + k;
        if (ll >= 0) acc = fmaf(conv_w[d * 4 + k], xz[(size_t)ll * 768 + d], acc);
    }
    float v = siluf_(acc);
    xs_l[d] = v;
    xsb[(size_t)l * DI + d] = f2bf(v);
    __syncthreads();
    int wv = d >> 6, lane = d & 63;
    for (int j = wv; j < 44; j += 6) {
        float p = 0.f;
        #pragma unroll
        for (int r = 0; r < 6; ++r) {
            int dd = lane + r * 64;
            p = fmaf(xs_l[dd], W_xp[(size_t)j * DI + dd], p);
        }
        p = wave_sum(p);
        if (lane == 0) xdbl[j] = p;
    }
    __syncthreads();
    float sdt = b_dt[d];
    #pragma unroll
    for (int r = 0; r < 12; ++r) sdt = fmaf(xdbl[r], W_dt[d * 12 + r], sdt);
    float dtv = (sdt > 20.f) ? sdt : LOG2(1.f + EXP2(sdt * L2E)) * LN2;
    dtb[(size_t)l * DI + d] = dtv;
    if (d < DS)            Bb[(size_t)l * DS + d] = xdbl[12 + d];
    else if (d < 2 * DS)   Cb[(size_t)l * DS + (d - DS)] = xdbl[28 + (d - DS)];
}

// ---------------- scan: s in registers, thread = one d-channel ----------------
__global__ __launch_bounds__(384) void scan1(const float* __restrict__ dtb,
                                             const unsigned short* __restrict__ xsb,
                                             const float* __restrict__ Bm,
                                             const float* __restrict__ Alog,
                                             float* __restrict__ chA,
                                             float* __restrict__ chB) {
    int d = threadIdx.x, c = blockIdx.x;
    __shared__ float Bs[CLEN * DS];       // 512 floats
    for (int i = d; i < CLEN * DS; i += 384) Bs[i] = Bm[(size_t)c * CLEN * DS + i];
    float A2[DS];
    #pragma unroll
    for (int s = 0; s < DS; ++s) A2[s] = -expf(Alog[d * DS + s]) * L2E;
    float h[DS] = {};
    float dts = 0.f;
    __syncthreads();
    #pragma unroll
    for (int i = 0; i < CLEN; ++i) {
        int l = c * CLEN + i;
        float dtv = dtb[(size_t)l * DI + d];
        float xv  = bf2f(xsb[(size_t)l * DI + d]);
        float dtx = dtv * xv;
        dts += dtv;
        #pragma unroll
        for (int s = 0; s < DS; ++s) {
            float a = EXP2(dtv * A2[s]);
            h[s] = fmaf(a, h[s], dtx * Bs[i * DS + s]);
        }
    }
    size_t base = (size_t)c * NLANE + d * DS;
    #pragma unroll
    for (int s = 0; s < DS; s += 4) {
        float4 pa, pb;
        pa.x = EXP2(dts * A2[s + 0]); pa.y = EXP2(dts * A2[s + 1]);
        pa.z = EXP2(dts * A2[s + 2]); pa.w = EXP2(dts * A2[s + 3]);
        pb.x = h[s + 0]; pb.y = h[s + 1]; pb.z = h[s + 2]; pb.w = h[s + 3];
        *(float4*)&chA[base + s] = pa;
        *(float4*)&chB[base + s] = pb;
    }
}

// phase2: serial prefix over chunks, 8-wide load batching to hide latency
__global__ __launch_bounds__(256) void scan2(const float* __restrict__ chA,
                                             const float* __restrict__ chB,
                                             float* __restrict__ hst) {
    int lane = blockIdx.x * 256 + threadIdx.x;   // 0..6143
    float h = 0.f;
    for (int c0 = 0; c0 < NCH; c0 += 8) {
        float a[8], b[8];
        #pragma unroll
        for (int u = 0; u < 8; ++u) {
            a[u] = chA[(size_t)(c0 + u) * NLANE + lane];
            b[u] = chB[(size_t)(c0 + u) * NLANE + lane];
        }
        #pragma unroll
        for (int u = 0; u < 8; ++u) {
            hst[(size_t)(c0 + u) * NLANE + lane] = h;
            h = fmaf(a[u], h, b[u]);
        }
    }
}

// phase3: re-scan with prefix, y = sum_s h*C, fused gate -> bf16 ybuf
__global__ __launch_bounds__(384) void scan3(const float* __restrict__ dtb,
                                             const unsigned short* __restrict__ xsb,
                                             const float* __restrict__ Bm,
                                             const float* __restrict__ Cm,
                                             const float* __restrict__ Alog,
                                             const float* __restrict__ hst,
                                             const float* __restrict__ xz,
                                             const float* __restrict__ Dvec,
                                             unsigned short* __restrict__ ybuf) {
    int d = threadIdx.x, c = blockIdx.x;
    __shared__ float Bs[CLEN * DS];
    __shared__ float Cs[CLEN * DS];
    for (int i = d; i < CLEN * DS; i += 384) {
        Bs[i] = Bm[(size_t)c * CLEN * DS + i];
        Cs[i] = Cm[(size_t)c * CLEN * DS + i];
    }
    float A2[DS];
    #pragma unroll
    for (int s = 0; s < DS; ++s) A2[s] = -expf(Alog[d * DS + s]) * L2E;
    float h[DS];
    size_t base = (size_t)c * NLANE + d * DS;
    #pragma unroll
    for (int s = 0; s < DS; s += 4) {
        float4 v = *(const float4*)&hst[base + s];
        h[s] = v.x; h[s + 1] = v.y; h[s + 2] = v.z; h[s + 3] = v.w;
    }
    float Dv = Dvec[d];
    __syncthreads();
    #pragma unroll
    for (int i = 0; i < CLEN; ++i) {
        int l = c * CLEN + i;
        float dtv = dtb[(size_t)l * DI + d];
        float xv  = bf2f(xsb[(size_t)l * DI + d]);
        float dtx = dtv * xv;
        float y = 0.f;
        #pragma unroll
        for (int s = 0; s < DS; ++s) {
            float a = EXP2(dtv * A2[s]);
            h[s] = fmaf(a, h[s], dtx * Bs[i * DS + s]);
            y = fmaf(h[s], Cs[i * DS + s], y);
        }
        float z = xz[(size_t)l * 768 + 384 + d];
        float val = (y + xv * Dv) * siluf_(z);
        ybuf[(size_t)l * DI + d] = f2bf(val);
    }
}

// ---------------- ln2 + residual + transposed store to o5[c][t][sp] ----------------
__global__ __launch_bounds__(192) void ln2_kernel(const float* __restrict__ tokens,
                                                  const float* __restrict__ gout,
                                                  const float* __restrict__ g,
                                                  const float* __restrict__ bb,
                                                  float* __restrict__ o5) {
    int l = blockIdx.x, c = threadIdx.x;
    __shared__ float sb[4];
    float xv = tokens[(size_t)l * DIMC + c] + gout[(size_t)l * DIMC + c];
    float s = wave_sum(xv);
    int wv = c >> 6;
    if ((c & 63) == 0) sb[wv] = s;
    __syncthreads();
    float m = (sb[0] + sb[1] + sb[2]) * (1.f / 192.f);
    float dx = xv - m;
    float s2 = wave_sum(dx * dx);
    __syncthreads();
    if ((c & 63) == 0) sb[wv] = s2;
    __syncthreads();
    float var = (sb[0] + sb[1] + sb[2]) * (1.f / 192.f);
    float val = dx * rsqrtf(var + 1e-5f) * g[c] + bb[c];
    int t = l >> 8, sp = l & 255;
    o5[((size_t)c * 16 + t) * 256 + sp] = val;
}

// ---------------- pooled mean + rfft bins 1..7 + sigmoid -> weight[c] ----------------
__global__ __launch_bounds__(256) void fft_kernel(const float* __restrict__ o5,
                                                  float* __restrict__ wgt) {
    int c = blockIdx.x;
    __shared__ float pooled[16];
    __shared__ float mag[8];
    int tid = threadIdx.x;
    int wv = tid >> 6, lane = tid & 63;
    for (int t = wv * 4; t < wv * 4 + 4; ++t) {
        float s = 0.f;
        #pragma unroll
        for (int r = 0; r < 4; ++r) s += o5[(size_t)c * 4096 + t * 256 + lane + r * 64];
        s = wave_sum(s);
        if (lane == 0) pooled[t] = s * (1.f / 256.f);
    }
    __syncthreads();
    if (tid >= 1 && tid <= 7) {
        int k = tid;
        float re = 0.f, im = 0.f;
        for (int t = 0; t < 16; ++t) {
            float ang = -0.39269908169872414f * (float)(k * t);
            re = fmaf(pooled[t], cosf(ang), re);
            im = fmaf(pooled[t], sinf(ang), im);
        }
        mag[k] = sqrtf(re * re + im * im);
    }
    __syncthreads();
    if (tid == 0) {
        float m = 0.f;
        for (int k = 1; k <= 7; ++k) m += mag[k];
        wgt[c] = sigmoidf_(m * (1.f / 7.f));
    }
}

// ---------------- trilinear 4x upsample, 4-wide in w ----------------
__global__ __launch_bounds__(256) void upsample_kernel(const float* __restrict__ o5,
                                                       const float* __restrict__ wgt,
                                                       const float* __restrict__ x,
                                                       float* __restrict__ out) {
    int idx = blockIdx.x * 256 + threadIdx.x;    // < 192*16*64*16
    int k  = idx & 15;
    int h  = (idx >> 4) & 63;
    int t  = (idx >> 10) & 15;
    int c  = idx >> 14;
    float sh = h * 0.25f - 0.375f;
    int h0 = (int)floorf(sh); float fh = sh - (float)h0;
    int h0c = min(max(h0, 0), 15), h1c = min(max(h0 + 1, 0), 15);
    const float* pl = o5 + ((size_t)c * 16 + t) * 256;
    int cm = max(k - 1, 0), cp = min(k + 1, 15);
    float r0m = pl[h0c * 16 + cm], r00 = pl[h0c * 16 + k], r0p = pl[h0c * 16 + cp];
    float r1m = pl[h1c * 16 + cm], r10 = pl[h1c * 16 + k], r1p = pl[h1c * 16 + cp];
    float gh = 1.f - fh;
    float vm = r0m * gh + r1m * fh;
    float v0 = r00 * gh + r10 * fh;
    float vp = r0p * gh + r1p * fh;
    float wc = wgt[c];
    size_t off = (size_t)idx * 4;
    float4 xv = *(const float4*)(x + off);
    float4 o;
    o.x = (vm * 0.375f + v0 * 0.625f) * wc * sigmoidf_(xv.x);
    o.y = (vm * 0.125f + v0 * 0.875f) * wc * sigmoidf_(xv.y);
    o.z = (v0 * 0.875f + vp * 0.125f) * wc * sigmoidf_(xv.z);
    o.w = (v0 * 0.625f + vp * 0.375f) * wc * sigmoidf_(xv.w);
    *(float4*)(out + off) = o;
}

extern "C" void kernel_launch(void* const* d_in, const int* in_sizes, int n_in,
                              void* d_out, int out_size, void* d_ws, size_t ws_size,
                              hipStream_t stream) {
    const float* x      = (const float*)d_in[0];
    const float* ln1_g  = (const float*)d_in[1];
    const float* ln1_b  = (const float*)d_in[2];
    const float* ln2_g  = (const float*)d_in[3];
    const float* ln2_b  = (const float*)d_in[4];
    const float* W_in   = (const float*)d_in[5];
    const float* conv_w = (const float*)d_in[6];
    const float* conv_b = (const float*)d_in[7];
    const float* W_xp   = (const float*)d_in[8];
    const float* W_dt   = (const float*)d_in[9];
    const float* b_dt   = (const float*)d_in[10];
    const float* A_log  = (const float*)d_in[11];
    const float* Dvec   = (const float*)d_in[12];
    const float* W_out  = (const float*)d_in[13];
    float* out = (float*)d_out;

    float* ws = (float*)d_ws;
    float* tokens = ws;  ws += (size_t)LTOK * DIMC;
    float* xz     = ws;  ws += (size_t)LTOK * 768;
    float* dtb    = ws;  ws += (size_t)LTOK * DI;
    float* Bb     = ws;  ws += (size_t)LTOK * DS;
    float* Cb     = ws;  ws += (size_t)LTOK * DS;
    float* chA    = ws;  ws += (size_t)NLANE * NCH;
    float* chB    = ws;  ws += (size_t)NLANE * NCH;
    float* hst    = ws;  ws += (size_t)NLANE * NCH;
    float* gout   = ws;  ws += (size_t)LTOK * DIMC;
    float* o5     = ws;  ws += (size_t)DIMC * LTOK;
    float* wgt    = ws;  ws += DIMC;
    unsigned short* ytok = (unsigned short*)ws;  ws += (size_t)LTOK * DIMC / 2;
    unsigned short* ybuf = (unsigned short*)ws;  ws += (size_t)LTOK * DI / 2;
    unsigned short* xsb  = (unsigned short*)ws;  ws += (size_t)LTOK * DI / 2;

    poolln_kernel<<<256, 256, 0, stream>>>(x, ln1_g, ln1_b, tokens, ytok);
    gemm_mfma<192><<<dim3(12, 64), 256, 0, stream>>>(ytok, W_in, xz, 768);
    conv_proj<<<LTOK, 384, 0, stream>>>(xz, conv_w, conv_b, W_xp, W_dt, b_dt, xsb, dtb, Bb, Cb);
    scan1<<<NCH, 384, 0, stream>>>(dtb, xsb, Bb, A_log, chA, chB);
    scan2<<<NLANE / 256, 256, 0, stream>>>(chA, chB, hst);
    scan3<<<NCH, 384, 0, stream>>>(dtb, xsb, Bb, Cb, A_log, hst, xz, Dvec, ybuf);
    gemm_mfma<384><<<dim3(3, 64), 256, 0, stream>>>(ybuf, W_out, gout, 192);
    ln2_kernel<<<LTOK, 192, 0, stream>>>(tokens, gout, ln2_g, ln2_b, o5);
    fft_kernel<<<192, 256, 0, stream>>>(o5, wgt);
    upsample_kernel<<<12288, 256, 0, stream>>>(o5, wgt, x, out);
}

// Round 5
// 140.443 us; speedup vs baseline: 1.4284x; 1.0083x over previous
//
#include <hip/hip_runtime.h>
#include <math.h>

#define DIMC 192
#define DI   384
#define DS   16
#define LTOK 4096
#define NCH  256
#define CLEN 16
#define NLANE (DI*DS)   // 6144
#define L2E  1.4426950408889634f
#define LN2  0.6931471805599453f

typedef __attribute__((ext_vector_type(8))) short    bf16x8;
typedef __attribute__((ext_vector_type(8))) unsigned short u16x8;
typedef __attribute__((ext_vector_type(4))) float    f32x4;

__device__ __forceinline__ float EXP2(float x) { return __builtin_amdgcn_exp2f(x); }
__device__ __forceinline__ float RCP(float x)  { return __builtin_amdgcn_rcpf(x); }
__device__ __forceinline__ float LOG2(float x) { return __builtin_amdgcn_logf(x); }

__device__ __forceinline__ float wave_sum(float v) {
    v += __shfl_xor(v, 1);
    v += __shfl_xor(v, 2);
    v += __shfl_xor(v, 4);
    v += __shfl_xor(v, 8);
    v += __shfl_xor(v, 16);
    v += __shfl_xor(v, 32);
    return v;
}

__device__ __forceinline__ float sigmoidf_(float x) { return RCP(1.f + EXP2(-x * L2E)); }
__device__ __forceinline__ float siluf_(float x)    { return x * RCP(1.f + EXP2(-x * L2E)); }
__device__ __forceinline__ unsigned short f2bf(float f) {
    unsigned int u = __float_as_uint(f);
    u += 0x7FFFu + ((u >> 16) & 1u);
    return (unsigned short)(u >> 16);
}
__device__ __forceinline__ float bf2f(unsigned short b) {
    return __uint_as_float(((unsigned int)b) << 16);
}

// ---------------- fused pool (1,4,4 mean) + ln1 -> tokens f32, ytok bf16 ----------------
__global__ __launch_bounds__(256) void poolln_kernel(const float* __restrict__ x,
                                                     const float* __restrict__ g,
                                                     const float* __restrict__ bb,
                                                     float* __restrict__ tokens,
                                                     unsigned short* __restrict__ ytok) {
    int blk = blockIdx.x;
    int t = blk >> 4, hs = blk & 15;
    int tid = threadIdx.x;
    int grp = tid >> 4, ws = tid & 15;
    __shared__ float P[16][200];
    __shared__ float ms[16], rs[16];
    #pragma unroll
    for (int k = 0; k < 12; ++k) {
        int c = grp + (k << 4);
        const float* base = x + ((size_t)(c * 16 + t) * 64 + hs * 4) * 64 + ws * 4;
        float s = 0.f;
        #pragma unroll
        for (int i = 0; i < 4; ++i) {
            float4 v = *(const float4*)(base + i * 64);
            s += v.x + v.y + v.z + v.w;
        }
        P[ws][c] = s * 0.0625f;
    }
    __syncthreads();
    float s1 = 0.f, s2 = 0.f;
    #pragma unroll
    for (int k = 0; k < 12; ++k) {
        float v = P[grp][ws + 16 * k];
        s1 += v; s2 += v * v;
    }
    s1 += __shfl_xor(s1, 1); s2 += __shfl_xor(s2, 1);
    s1 += __shfl_xor(s1, 2); s2 += __shfl_xor(s2, 2);
    s1 += __shfl_xor(s1, 4); s2 += __shfl_xor(s2, 4);
    s1 += __shfl_xor(s1, 8); s2 += __shfl_xor(s2, 8);
    if (ws == 0) {
        float m = s1 * (1.f / 192.f);
        ms[grp] = m;
        rs[grp] = rsqrtf(s2 * (1.f / 192.f) - m * m + 1e-5f);
    }
    __syncthreads();
    int l0 = t * 256 + hs * 16;
    for (int e = tid; e < 16 * 192; e += 256) {
        int w2 = e / 192, c = e - w2 * 192;
        float v = P[w2][c];
        float val = (v - ms[w2]) * rs[w2] * g[c] + bb[c];
        tokens[(size_t)(l0 + w2) * DIMC + c] = v;
        ytok[(size_t)(l0 + w2) * DIMC + c] = f2bf(val);
    }
}

// ---------------- MFMA GEMM: C[m][n] = sum_k A_bf16[m][k] * W_f32[n][k] ----------------
template<int K>
__global__ __launch_bounds__(256) void gemm_mfma(const unsigned short* __restrict__ A,
                                                 const float* __restrict__ W,
                                                 float* __restrict__ Cout,
                                                 int N) {
    constexpr int KP = K + 8;
    __shared__ unsigned short As[64 * KP];
    __shared__ unsigned short Bs[64 * KP];
    int bm = blockIdx.y * 64;
    int bn = blockIdx.x * 64;
    int tid = threadIdx.x;
    for (int c = tid; c < 64 * (K / 8); c += 256) {
        int row = c / (K / 8), col = (c % (K / 8)) * 8;
        u16x8 v = *(const u16x8*)(A + (size_t)(bm + row) * K + col);
        *(u16x8*)&As[row * KP + col] = v;
    }
    for (int c = tid; c < 64 * (K / 4); c += 256) {
        int row = c / (K / 4), col = (c % (K / 4)) * 4;
        float4 v = *(const float4*)(W + (size_t)(bn + row) * K + col);
        ushort4 b;
        b.x = f2bf(v.x); b.y = f2bf(v.y); b.z = f2bf(v.z); b.w = f2bf(v.w);
        *(ushort4*)&Bs[row * KP + col] = b;
    }
    __syncthreads();
    int lane = tid & 63, w = tid >> 6;
    int wr = w >> 1, wc = w & 1;
    int r16 = lane & 15, h = lane >> 4;
    f32x4 acc[2][2] = {};
    #pragma unroll
    for (int k0 = 0; k0 < K; k0 += 32) {
        bf16x8 a0 = *(const bf16x8*)&As[(wr * 32 + r16)      * KP + k0 + 8 * h];
        bf16x8 a1 = *(const bf16x8*)&As[(wr * 32 + 16 + r16) * KP + k0 + 8 * h];
        bf16x8 b0 = *(const bf16x8*)&Bs[(wc * 32 + r16)      * KP + k0 + 8 * h];
        bf16x8 b1 = *(const bf16x8*)&Bs[(wc * 32 + 16 + r16) * KP + k0 + 8 * h];
        acc[0][0] = __builtin_amdgcn_mfma_f32_16x16x32_bf16(a0, b0, acc[0][0], 0, 0, 0);
        acc[0][1] = __builtin_amdgcn_mfma_f32_16x16x32_bf16(a0, b1, acc[0][1], 0, 0, 0);
        acc[1][0] = __builtin_amdgcn_mfma_f32_16x16x32_bf16(a1, b0, acc[1][0], 0, 0, 0);
        acc[1][1] = __builtin_amdgcn_mfma_f32_16x16x32_bf16(a1, b1, acc[1][1], 0, 0, 0);
    }
    #pragma unroll
    for (int fm = 0; fm < 2; ++fm)
        #pragma unroll
        for (int fn = 0; fn < 2; ++fn)
            #pragma unroll
            for (int i = 0; i < 4; ++i) {
                int r = bm + wr * 32 + fm * 16 + h * 4 + i;
                int cc = bn + wc * 32 + fn * 16 + r16;
                Cout[(size_t)r * N + cc] = acc[fm][fn][i];
            }
}

// ---------------- conv (causal depthwise, k=4) + silu + x_dbl proj + dt ----------------
__global__ __launch_bounds__(384) void conv_proj(const float* __restrict__ xz,
                                                 const float* __restrict__ conv_w,
                                                 const float* __restrict__ conv_b,
                                                 const float* __restrict__ W_xp,
                                                 const float* __restrict__ W_dt,
                                                 const float* __restrict__ b_dt,
                                                 unsigned short* __restrict__ xsb,
                                                 float* __restrict__ dtb,
                                                 float* __restrict__ Bb,
                                                 float* __restrict__ Cb) {
    int l = blockIdx.x;
    int d = threadIdx.x;           // 0..383
    __shared__ float xs_l[DI];
    __shared__ float xdbl[44];
    float acc = conv_b[d];
    #pragma unroll
    for (int k = 0; k < 4; ++k) {
        int ll = l - 3 + k;
        if (ll >= 0) acc = fmaf(conv_w[d * 4 + k], xz[(size_t)ll * 768 + d], acc);
    }
    float v = siluf_(acc);
    xs_l[d] = v;
    xsb[(size_t)l * DI + d] = f2bf(v);
    __syncthreads();
    int wv = d >> 6, lane = d & 63;
    for (int j = wv; j < 44; j += 6) {
        float p = 0.f;
        #pragma unroll
        for (int r = 0; r < 6; ++r) {
            int dd = lane + r * 64;
            p = fmaf(xs_l[dd], W_xp[(size_t)j * DI + dd], p);
        }
        p = wave_sum(p);
        if (lane == 0) xdbl[j] = p;
    }
    __syncthreads();
    float sdt = b_dt[d];
    #pragma unroll
    for (int r = 0; r < 12; ++r) sdt = fmaf(xdbl[r], W_dt[d * 12 + r], sdt);
    float dtv = (sdt > 20.f) ? sdt : LOG2(1.f + EXP2(sdt * L2E)) * LN2;
    dtb[(size_t)l * DI + d] = dtv;
    if (d < DS)            Bb[(size_t)l * DS + d] = xdbl[12 + d];
    else if (d < 2 * DS)   Cb[(size_t)l * DS + (d - DS)] = xdbl[28 + (d - DS)];
}

// ---------------- scan1: thread=(d, s-quad); local scan + y_local + Dloc + summaries ----
// block 256 = 64 d x 4 sq; grid (DI/64=6, NCH)
__global__ __launch_bounds__(256) void scan1(const float* __restrict__ dtb,
                                             const unsigned short* __restrict__ xsb,
                                             const float* __restrict__ Bm,
                                             const float* __restrict__ Cm,
                                             const float* __restrict__ Alog,
                                             float* __restrict__ chA,
                                             float* __restrict__ chB,
                                             float* __restrict__ Dloc,
                                             unsigned short* __restrict__ yloc) {
    int tid = threadIdx.x;
    int sq = tid & 3, dl = tid >> 2;          // sq: s-quad, dl: 0..63
    int d = blockIdx.x * 64 + dl;
    int c = blockIdx.y;
    __shared__ float Bs[CLEN * DS];           // 256
    __shared__ float Cs[CLEN * DS];           // 256
    Bs[tid] = Bm[(size_t)c * CLEN * DS + tid];
    Cs[tid] = Cm[(size_t)c * CLEN * DS + tid];
    float4 al = *(const float4*)(Alog + (size_t)d * DS + sq * 4);
    float A2[4];
    A2[0] = -expf(al.x) * L2E; A2[1] = -expf(al.y) * L2E;
    A2[2] = -expf(al.z) * L2E; A2[3] = -expf(al.w) * L2E;
    float h[4] = {};
    float dts = 0.f;
    __syncthreads();
    #pragma unroll
    for (int i = 0; i < CLEN; ++i) {
        int l = c * CLEN + i;
        float dtv = dtb[(size_t)l * DI + d];
        float xv  = bf2f(xsb[(size_t)l * DI + d]);
        float dtx = dtv * xv;
        dts += dtv;
        float y = 0.f;
        #pragma unroll
        for (int u = 0; u < 4; ++u) {
            float a = EXP2(dtv * A2[u]);
            h[u] = fmaf(a, h[u], dtx * Bs[i * DS + sq * 4 + u]);
            y = fmaf(h[u], Cs[i * DS + sq * 4 + u], y);
        }
        y += __shfl_xor(y, 1);
        y += __shfl_xor(y, 2);
        if (sq == 0) {
            yloc[(size_t)l * DI + d] = f2bf(y);
            Dloc[(size_t)l * DI + d] = dts;
        }
    }
    size_t base = (size_t)c * NLANE + d * DS + sq * 4;
    float4 pa, pb;
    pa.x = EXP2(dts * A2[0]); pa.y = EXP2(dts * A2[1]);
    pa.z = EXP2(dts * A2[2]); pa.w = EXP2(dts * A2[3]);
    pb.x = h[0]; pb.y = h[1]; pb.z = h[2]; pb.w = h[3];
    *(float4*)&chA[base] = pa;
    *(float4*)&chB[base] = pb;
}

// scan2: serial prefix over chunks, 8-wide load batching
__global__ __launch_bounds__(256) void scan2(const float* __restrict__ chA,
                                             const float* __restrict__ chB,
                                             float* __restrict__ hst) {
    int lane = blockIdx.x * 256 + threadIdx.x;   // 0..6143
    float h = 0.f;
    for (int c0 = 0; c0 < NCH; c0 += 8) {
        float a[8], b[8];
        #pragma unroll
        for (int u = 0; u < 8; ++u) {
            a[u] = chA[(size_t)(c0 + u) * NLANE + lane];
            b[u] = chB[(size_t)(c0 + u) * NLANE + lane];
        }
        #pragma unroll
        for (int u = 0; u < 8; ++u) {
            hst[(size_t)(c0 + u) * NLANE + lane] = h;
            h = fmaf(a[u], h, b[u]);
        }
    }
}

// scan3fix: elementwise fix-up + gate. block 256 = 16 l x 16 d; grid (DI/16=24, NCH)
__global__ __launch_bounds__(256) void scan3fix(const float* __restrict__ hst,
                                                const float* __restrict__ Dloc,
                                                const float* __restrict__ Cm,
                                                const float* __restrict__ Alog,
                                                const unsigned short* __restrict__ xsb,
                                                const float* __restrict__ xz,
                                                const float* __restrict__ Dvec,
                                                unsigned short* __restrict__ ybuf) {
    int dg = blockIdx.x;        // 0..23
    int c  = blockIdx.y;        // 0..NCH-1
    int tid = threadIdx.x;
    int ll = tid >> 4, dl = tid & 15;
    int d = dg * 16 + dl;
    int l = c * 16 + ll;
    __shared__ float hpS[16][17];
    __shared__ float A2S[16][17];
    __shared__ float CsS[256];
    {
        int dd = tid >> 4, ss = tid & 15;
        hpS[dd][ss] = hst[(size_t)c * NLANE + dg * 256 + tid];
        A2S[dd][ss] = -expf(Alog[(size_t)dg * 256 + tid]) * L2E;
        CsS[tid]    = Cm[(size_t)c * 256 + tid];
    }
    __syncthreads();
    float Dl = Dloc[(size_t)l * DI + d];
    float y  = bf2f(ybuf[(size_t)l * DI + d]);
    float xv = bf2f(xsb[(size_t)l * DI + d]);
    float z  = xz[(size_t)l * 768 + 384 + d];
    #pragma unroll
    for (int s = 0; s < 16; ++s) {
        float e = EXP2(A2S[dl][s] * Dl);
        y = fmaf(CsS[ll * 16 + s] * e, hpS[dl][s], y);
    }
    float val = (y + xv * Dvec[d]) * siluf_(z);
    ybuf[(size_t)l * DI + d] = f2bf(val);
}

// ---------------- ln2 + residual + transposed store to o5[c][t][sp] ----------------
__global__ __launch_bounds__(192) void ln2_kernel(const float* __restrict__ tokens,
                                                  const float* __restrict__ gout,
                                                  const float* __restrict__ g,
                                                  const float* __restrict__ bb,
                                                  float* __restrict__ o5) {
    int l = blockIdx.x, c = threadIdx.x;
    __shared__ float sb[4];
    float xv = tokens[(size_t)l * DIMC + c] + gout[(size_t)l * DIMC + c];
    float s = wave_sum(xv);
    int wv = c >> 6;
    if ((c & 63) == 0) sb[wv] = s;
    __syncthreads();
    float m = (sb[0] + sb[1] + sb[2]) * (1.f / 192.f);
    float dx = xv - m;
    float s2 = wave_sum(dx * dx);
    __syncthreads();
    if ((c & 63) == 0) sb[wv] = s2;
    __syncthreads();
    float var = (sb[0] + sb[1] + sb[2]) * (1.f / 192.f);
    float val = dx * rsqrtf(var + 1e-5f) * g[c] + bb[c];
    int t = l >> 8, sp = l & 255;
    o5[((size_t)c * 16 + t) * 256 + sp] = val;
}

// ---------------- pooled mean + rfft bins 1..7 + sigmoid -> weight[c] ----------------
__global__ __launch_bounds__(256) void fft_kernel(const float* __restrict__ o5,
                                                  float* __restrict__ wgt) {
    int c = blockIdx.x;
    __shared__ float pooled[16];
    __shared__ float mag[8];
    int tid = threadIdx.x;
    int wv = tid >> 6, lane = tid & 63;
    for (int t = wv * 4; t < wv * 4 + 4; ++t) {
        float s = 0.f;
        #pragma unroll
        for (int r = 0; r < 4; ++r) s += o5[(size_t)c * 4096 + t * 256 + lane + r * 64];
        s = wave_sum(s);
        if (lane == 0) pooled[t] = s * (1.f / 256.f);
    }
    __syncthreads();
    if (tid >= 1 && tid <= 7) {
        int k = tid;
        float re = 0.f, im = 0.f;
        for (int t = 0; t < 16; ++t) {
            float ang = -0.39269908169872414f * (float)(k * t);
            re = fmaf(pooled[t], cosf(ang), re);
            im = fmaf(pooled[t], sinf(ang), im);
        }
        mag[k] = sqrtf(re * re + im * im);
    }
    __syncthreads();
    if (tid == 0) {
        float m = 0.f;
        for (int k = 1; k <= 7; ++k) m += mag[k];
        wgt[c] = sigmoidf_(m * (1.f / 7.f));
    }
}

// ---------------- trilinear 4x upsample, 4-wide in w ----------------
__global__ __launch_bounds__(256) void upsample_kernel(const float* __restrict__ o5,
                                                       const float* __restrict__ wgt,
                                                       const float* __restrict__ x,
                                                       float* __restrict__ out) {
    int idx = blockIdx.x * 256 + threadIdx.x;    // < 192*16*64*16
    int k  = idx & 15;
    int h  = (idx >> 4) & 63;
    int t  = (idx >> 10) & 15;
    int c  = idx >> 14;
    float sh = h * 0.25f - 0.375f;
    int h0 = (int)floorf(sh); float fh = sh - (float)h0;
    int h0c = min(max(h0, 0), 15), h1c = min(max(h0 + 1, 0), 15);
    const float* pl = o5 + ((size_t)c * 16 + t) * 256;
    int cm = max(k - 1, 0), cp = min(k + 1, 15);
    float r0m = pl[h0c * 16 + cm], r00 = pl[h0c * 16 + k], r0p = pl[h0c * 16 + cp];
    float r1m = pl[h1c * 16 + cm], r10 = pl[h1c * 16 + k], r1p = pl[h1c * 16 + cp];
    float gh = 1.f - fh;
    float vm = r0m * gh + r1m * fh;
    float v0 = r00 * gh + r10 * fh;
    float vp = r0p * gh + r1p * fh;
    float wc = wgt[c];
    size_t off = (size_t)idx * 4;
    float4 xv = *(const float4*)(x + off);
    float4 o;
    o.x = (vm * 0.375f + v0 * 0.625f) * wc * sigmoidf_(xv.x);
    o.y = (vm * 0.125f + v0 * 0.875f) * wc * sigmoidf_(xv.y);
    o.z = (v0 * 0.875f + vp * 0.125f) * wc * sigmoidf_(xv.z);
    o.w = (v0 * 0.625f + vp * 0.375f) * wc * sigmoidf_(xv.w);
    *(float4*)(out + off) = o;
}

extern "C" void kernel_launch(void* const* d_in, const int* in_sizes, int n_in,
                              void* d_out, int out_size, void* d_ws, size_t ws_size,
                              hipStream_t stream) {
    const float* x      = (const float*)d_in[0];
    const float* ln1_g  = (const float*)d_in[1];
    const float* ln1_b  = (const float*)d_in[2];
    const float* ln2_g  = (const float*)d_in[3];
    const float* ln2_b  = (const float*)d_in[4];
    const float* W_in   = (const float*)d_in[5];
    const float* conv_w = (const float*)d_in[6];
    const float* conv_b = (const float*)d_in[7];
    const float* W_xp   = (const float*)d_in[8];
    const float* W_dt   = (const float*)d_in[9];
    const float* b_dt   = (const float*)d_in[10];
    const float* A_log  = (const float*)d_in[11];
    const float* Dvec   = (const float*)d_in[12];
    const float* W_out  = (const float*)d_in[13];
    float* out = (float*)d_out;

    float* ws = (float*)d_ws;
    float* tokens = ws;  ws += (size_t)LTOK * DIMC;
    float* xz     = ws;  ws += (size_t)LTOK * 768;
    float* dtb    = ws;  ws += (size_t)LTOK * DI;
    float* Bb     = ws;  ws += (size_t)LTOK * DS;
    float* Cb     = ws;  ws += (size_t)LTOK * DS;
    float* chA    = ws;  ws += (size_t)NLANE * NCH;
    float* chB    = ws;  ws += (size_t)NLANE * NCH;
    float* hst    = ws;  ws += (size_t)NLANE * NCH;
    float* Dloc   = ws;  ws += (size_t)LTOK * DI;
    float* gout   = ws;  ws += (size_t)LTOK * DIMC;
    float* o5     = ws;  ws += (size_t)DIMC * LTOK;
    float* wgt    = ws;  ws += DIMC;
    unsigned short* ytok = (unsigned short*)ws;  ws += (size_t)LTOK * DIMC / 2;
    unsigned short* ybuf = (unsigned short*)ws;  ws += (size_t)LTOK * DI / 2;
    unsigned short* xsb  = (unsigned short*)ws;  ws += (size_t)LTOK * DI / 2;

    poolln_kernel<<<256, 256, 0, stream>>>(x, ln1_g, ln1_b, tokens, ytok);
    gemm_mfma<192><<<dim3(12, 64), 256, 0, stream>>>(ytok, W_in, xz, 768);
    conv_proj<<<LTOK, 384, 0, stream>>>(xz, conv_w, conv_b, W_xp, W_dt, b_dt, xsb, dtb, Bb, Cb);
    scan1<<<dim3(6, NCH), 256, 0, stream>>>(dtb, xsb, Bb, Cb, A_log, chA, chB, Dloc, ybuf);
    scan2<<<NLANE / 256, 256, 0, stream>>>(chA, chB, hst);
    scan3fix<<<dim3(24, NCH), 256, 0, stream>>>(hst, Dloc, Cb, A_log, xsb, xz, Dvec, ybuf);
    gemm_mfma<384><<<dim3(3, 64), 256, 0, stream>>>(ybuf, W_out, gout, 192);
    ln2_kernel<<<LTOK, 192, 0, stream>>>(tokens, gout, ln2_g, ln2_b, o5);
    fft_kernel<<<192, 256, 0, stream>>>(o5, wgt);
    upsample_kernel<<<12288, 256, 0, stream>>>(o5, wgt, x, out);
}

// Round 6
// 124.937 us; speedup vs baseline: 1.6057x; 1.1241x over previous
//
#include <hip/hip_runtime.h>
#include <math.h>

#define DIMC 192
#define DI   384
#define DS   16
#define LTOK 4096
#define NCH  256
#define CLEN 16
#define NLANE (DI*DS)   // 6144
#define L2E  1.4426950408889634f
#define LN2  0.6931471805599453f

typedef __attribute__((ext_vector_type(8))) short    bf16x8;
typedef __attribute__((ext_vector_type(8))) unsigned short u16x8;
typedef __attribute__((ext_vector_type(4))) float    f32x4;

__device__ __forceinline__ float EXP2(float x) { return __builtin_amdgcn_exp2f(x); }
__device__ __forceinline__ float RCP(float x)  { return __builtin_amdgcn_rcpf(x); }
__device__ __forceinline__ float LOG2(float x) { return __builtin_amdgcn_logf(x); }

__device__ __forceinline__ float sigmoidf_(float x) { return RCP(1.f + EXP2(-x * L2E)); }
__device__ __forceinline__ float siluf_(float x)    { return x * RCP(1.f + EXP2(-x * L2E)); }
__device__ __forceinline__ unsigned short f2bf(float f) {
    unsigned int u = __float_as_uint(f);
    u += 0x7FFFu + ((u >> 16) & 1u);
    return (unsigned short)(u >> 16);
}
__device__ __forceinline__ float bf2f(unsigned short b) {
    return __uint_as_float(((unsigned int)b) << 16);
}

// ---- fused pool+ln1 (blocks 0..255) + one-time weight prep (blocks 256..287) ----
__global__ __launch_bounds__(256) void poolln_kernel(const float* __restrict__ x,
                                                     const float* __restrict__ g,
                                                     const float* __restrict__ bb,
                                                     const float* __restrict__ W_in,
                                                     const float* __restrict__ W_out,
                                                     const float* __restrict__ W_xp,
                                                     const float* __restrict__ A_log,
                                                     float* __restrict__ tokens,
                                                     unsigned short* __restrict__ ytok,
                                                     unsigned short* __restrict__ W_in_bf,
                                                     unsigned short* __restrict__ W_out_bf,
                                                     unsigned short* __restrict__ W_xp_pad,
                                                     float* __restrict__ A2pre) {
    int blk = blockIdx.x;
    int tid = threadIdx.x;
    if (blk >= 256) {   // prep path
        int id = (blk - 256) * 256 + tid;     // 0..8191
        for (int i = id; i < 768 * 192; i += 8192) W_in_bf[i] = f2bf(W_in[i]);
        for (int i = id; i < 192 * 384; i += 8192) W_out_bf[i] = f2bf(W_out[i]);
        for (int i = id; i < 64 * 384; i += 8192) {
            int row = i / 384;
            W_xp_pad[i] = (row < 44) ? f2bf(W_xp[i]) : (unsigned short)0;
        }
        for (int i = id; i < NLANE; i += 8192) A2pre[i] = -expf(A_log[i]) * L2E;
        return;
    }
    int t = blk >> 4, hs = blk & 15;
    int grp = tid >> 4, ws = tid & 15;
    __shared__ float P[16 * 196];
    __shared__ float ms[16], rs[16];
    #pragma unroll
    for (int k = 0; k < 12; ++k) {
        int c = grp + (k << 4);
        const float* base = x + ((size_t)(c * 16 + t) * 64 + hs * 4) * 64 + ws * 4;
        float s = 0.f;
        #pragma unroll
        for (int i = 0; i < 4; ++i) {
            float4 v = *(const float4*)(base + i * 64);
            s += v.x + v.y + v.z + v.w;
        }
        P[ws * 196 + c] = s * 0.0625f;
    }
    __syncthreads();
    float s1 = 0.f, s2 = 0.f;
    #pragma unroll
    for (int k = 0; k < 12; ++k) {
        float v = P[grp * 196 + ws + 16 * k];
        s1 += v; s2 += v * v;
    }
    s1 += __shfl_xor(s1, 1); s2 += __shfl_xor(s2, 1);
    s1 += __shfl_xor(s1, 2); s2 += __shfl_xor(s2, 2);
    s1 += __shfl_xor(s1, 4); s2 += __shfl_xor(s2, 4);
    s1 += __shfl_xor(s1, 8); s2 += __shfl_xor(s2, 8);
    if (ws == 0) {
        float m = s1 * (1.f / 192.f);
        ms[grp] = m;
        rs[grp] = rsqrtf(s2 * (1.f / 192.f) - m * m + 1e-5f);
    }
    __syncthreads();
    int l0 = t * 256 + hs * 16;
    for (int e = tid; e < 16 * 192; e += 256) {
        int w2 = e / 192, c = e - w2 * 192;
        float v = P[w2 * 196 + c];
        float val = (v - ms[w2]) * rs[w2] * g[c] + bb[c];
        tokens[(size_t)(l0 + w2) * DIMC + c] = v;
        ytok[(size_t)(l0 + w2) * DIMC + c] = f2bf(val);
    }
}

// ---- MFMA GEMM: C[m][n] = sum_k A_bf16[m][k] * W_bf16[n][k] ----
template<int K>
__global__ __launch_bounds__(256) void gemm_mfma(const unsigned short* __restrict__ A,
                                                 const unsigned short* __restrict__ Wb,
                                                 float* __restrict__ Cout,
                                                 int N) {
    constexpr int KP = K + 8;
    __shared__ unsigned short As[64 * KP];
    __shared__ unsigned short Bs[64 * KP];
    int bm = blockIdx.y * 64;
    int bn = blockIdx.x * 64;
    int tid = threadIdx.x;
    for (int c = tid; c < 64 * (K / 8); c += 256) {
        int row = c / (K / 8), col = (c % (K / 8)) * 8;
        *(u16x8*)&As[row * KP + col] = *(const u16x8*)(A + (size_t)(bm + row) * K + col);
        *(u16x8*)&Bs[row * KP + col] = *(const u16x8*)(Wb + (size_t)(bn + row) * K + col);
    }
    __syncthreads();
    int lane = tid & 63, w = tid >> 6;
    int wr = w >> 1, wc = w & 1;
    int r16 = lane & 15, h = lane >> 4;
    f32x4 acc[2][2] = {};
    #pragma unroll
    for (int k0 = 0; k0 < K; k0 += 32) {
        bf16x8 a0 = *(const bf16x8*)&As[(wr * 32 + r16)      * KP + k0 + 8 * h];
        bf16x8 a1 = *(const bf16x8*)&As[(wr * 32 + 16 + r16) * KP + k0 + 8 * h];
        bf16x8 b0 = *(const bf16x8*)&Bs[(wc * 32 + r16)      * KP + k0 + 8 * h];
        bf16x8 b1 = *(const bf16x8*)&Bs[(wc * 32 + 16 + r16) * KP + k0 + 8 * h];
        acc[0][0] = __builtin_amdgcn_mfma_f32_16x16x32_bf16(a0, b0, acc[0][0], 0, 0, 0);
        acc[0][1] = __builtin_amdgcn_mfma_f32_16x16x32_bf16(a0, b1, acc[0][1], 0, 0, 0);
        acc[1][0] = __builtin_amdgcn_mfma_f32_16x16x32_bf16(a1, b0, acc[1][0], 0, 0, 0);
        acc[1][1] = __builtin_amdgcn_mfma_f32_16x16x32_bf16(a1, b1, acc[1][1], 0, 0, 0);
    }
    #pragma unroll
    for (int fm = 0; fm < 2; ++fm)
        #pragma unroll
        for (int fn = 0; fn < 2; ++fn)
            #pragma unroll
            for (int i = 0; i < 4; ++i) {
                int r = bm + wr * 32 + fm * 16 + h * 4 + i;
                int cc = bn + wc * 32 + fn * 16 + r16;
                Cout[(size_t)r * N + cc] = acc[fm][fn][i];
            }
}

// ---- conv(k=4 causal)+silu -> xsb, then MFMA x_dbl = xs @ W_xp_pad^T (N=64) ----
__global__ __launch_bounds__(256) void convxdbl(const float* __restrict__ xz,
                                                const float* __restrict__ conv_w,
                                                const float* __restrict__ conv_b,
                                                const unsigned short* __restrict__ Wxp,
                                                unsigned short* __restrict__ xsb,
                                                float* __restrict__ x_dbl) {
    int l0 = blockIdx.x * 16;
    int tid = threadIdx.x;
    __shared__ unsigned short As[16 * 392];
    __shared__ float xd[16 * 64];
    for (int e = tid * 2; e < 16 * 384; e += 512) {
        int row = e / 384, d = e - row * 384;
        int l = l0 + row;
        float ax = conv_b[d], ay = conv_b[d + 1];
        #pragma unroll
        for (int k = 0; k < 4; ++k) {
            int ll = l - 3 + k;
            if (ll >= 0) {
                float2 v = *(const float2*)(xz + (size_t)ll * 768 + d);
                ax = fmaf(conv_w[d * 4 + k],       v.x, ax);
                ay = fmaf(conv_w[(d + 1) * 4 + k], v.y, ay);
            }
        }
        ushort2 b2;
        b2.x = f2bf(siluf_(ax));
        b2.y = f2bf(siluf_(ay));
        *(ushort2*)&As[row * 392 + d] = b2;
        *(ushort2*)(xsb + (size_t)l * 384 + d) = b2;
    }
    __syncthreads();
    int lane = tid & 63, w = tid >> 6;
    int r16 = lane & 15, hh = lane >> 4;
    f32x4 acc = {};
    #pragma unroll
    for (int k0 = 0; k0 < 384; k0 += 32) {
        bf16x8 a = *(const bf16x8*)&As[r16 * 392 + k0 + 8 * hh];
        bf16x8 b = *(const bf16x8*)(Wxp + (size_t)(w * 16 + r16) * 384 + k0 + 8 * hh);
        acc = __builtin_amdgcn_mfma_f32_16x16x32_bf16(a, b, acc, 0, 0, 0);
    }
    #pragma unroll
    for (int i = 0; i < 4; ++i) xd[(hh * 4 + i) * 64 + w * 16 + r16] = acc[i];
    __syncthreads();
    {
        int e = tid * 4;
        int row = e >> 6, col = e & 63;
        *(float4*)(x_dbl + (size_t)(l0 + row) * 64 + col) = *(const float4*)&xd[e];
    }
}

// ---- scan1: compute dt in-block from x_dbl; local scan + y_local + Dloc + summaries ----
// block 256 = (sq 4) x (dl 64); grid (6 d-groups, NCH chunks)
__global__ __launch_bounds__(256) void scan1(const float* __restrict__ x_dbl,
                                             const unsigned short* __restrict__ xsb,
                                             const float* __restrict__ W_dt,
                                             const float* __restrict__ b_dt,
                                             const float* __restrict__ A2pre,
                                             float* __restrict__ chA,
                                             float* __restrict__ chB,
                                             float* __restrict__ Dloc,
                                             unsigned short* __restrict__ yloc) {
    int tid = threadIdx.x;
    int dg = blockIdx.x;          // 0..5
    int c  = blockIdx.y;          // 0..NCH-1
    __shared__ float xdblS[16 * 48];
    __shared__ float wdtS[64 * 13];
    __shared__ float dtS[16][64];
    __shared__ unsigned short xsS[16][64];
    for (int i = tid; i < 768; i += 256) {
        int row = i / 48, col = i - row * 48;
        xdblS[i] = x_dbl[(size_t)(c * 16 + row) * 64 + col];
    }
    for (int i = tid; i < 768; i += 256) {
        int dl_ = i / 12, r = i - dl_ * 12;
        wdtS[dl_ * 13 + r] = W_dt[(size_t)dg * 768 + i];
    }
    for (int i = tid; i < 1024; i += 256) {
        int row = i >> 6, dl_ = i & 63;
        xsS[row][dl_] = xsb[(size_t)(c * 16 + row) * 384 + dg * 64 + dl_];
    }
    __syncthreads();
    {
        int dl_ = tid & 63;
        float bd = b_dt[dg * 64 + dl_];
        #pragma unroll
        for (int i2 = 0; i2 < 4; ++i2) {
            int row = (tid >> 6) + 4 * i2;
            float s = bd;
            #pragma unroll
            for (int r = 0; r < 12; ++r)
                s = fmaf(xdblS[row * 48 + r], wdtS[dl_ * 13 + r], s);
            dtS[row][dl_] = (s > 20.f) ? s : LOG2(1.f + EXP2(s * L2E)) * LN2;
        }
    }
    __syncthreads();
    int sq = tid & 3, dl = tid >> 2;
    int d = dg * 64 + dl;
    float4 a4 = *(const float4*)(A2pre + (size_t)d * DS + sq * 4);
    float A2[4] = {a4.x, a4.y, a4.z, a4.w};
    float h[4] = {};
    float dts = 0.f;
    #pragma unroll
    for (int i = 0; i < CLEN; ++i) {
        int l = c * CLEN + i;
        float dtv = dtS[i][dl];
        float xv  = bf2f(xsS[i][dl]);
        float dtx = dtv * xv;
        dts += dtv;
        float y = 0.f;
        #pragma unroll
        for (int u = 0; u < 4; ++u) {
            float a = EXP2(dtv * A2[u]);
            h[u] = fmaf(a, h[u], dtx * xdblS[i * 48 + 12 + sq * 4 + u]);
            y = fmaf(h[u], xdblS[i * 48 + 28 + sq * 4 + u], y);
        }
        y += __shfl_xor(y, 1);
        y += __shfl_xor(y, 2);
        if (sq == 0) {
            yloc[(size_t)l * DI + d] = f2bf(y);
            Dloc[(size_t)l * DI + d] = dts;
        }
    }
    size_t base = (size_t)c * NLANE + d * DS + sq * 4;
    float4 pa, pb;
    pa.x = EXP2(dts * A2[0]); pa.y = EXP2(dts * A2[1]);
    pa.z = EXP2(dts * A2[2]); pa.w = EXP2(dts * A2[3]);
    pb.x = h[0]; pb.y = h[1]; pb.z = h[2]; pb.w = h[3];
    *(float4*)&chA[base] = pa;
    *(float4*)&chB[base] = pb;
}

// scan2: serial prefix over chunks, 8-wide load batching
__global__ __launch_bounds__(256) void scan2(const float* __restrict__ chA,
                                             const float* __restrict__ chB,
                                             float* __restrict__ hst) {
    int lane = blockIdx.x * 256 + threadIdx.x;   // 0..6143
    float h = 0.f;
    for (int c0 = 0; c0 < NCH; c0 += 8) {
        float a[8], b[8];
        #pragma unroll
        for (int u = 0; u < 8; ++u) {
            a[u] = chA[(size_t)(c0 + u) * NLANE + lane];
            b[u] = chB[(size_t)(c0 + u) * NLANE + lane];
        }
        #pragma unroll
        for (int u = 0; u < 8; ++u) {
            hst[(size_t)(c0 + u) * NLANE + lane] = h;
            h = fmaf(a[u], h, b[u]);
        }
    }
}

// scan3fix: elementwise fix-up + gate. block 256 = 16 l x 16 d; grid (24, NCH)
__global__ __launch_bounds__(256) void scan3fix(const float* __restrict__ hst,
                                                const float* __restrict__ Dloc,
                                                const float* __restrict__ x_dbl,
                                                const float* __restrict__ A2pre,
                                                const unsigned short* __restrict__ xsb,
                                                const float* __restrict__ xz,
                                                const float* __restrict__ Dvec,
                                                unsigned short* __restrict__ ybuf) {
    int dg = blockIdx.x;        // 0..23
    int c  = blockIdx.y;        // 0..NCH-1
    int tid = threadIdx.x;
    int ll = tid >> 4, dl = tid & 15;
    int d = dg * 16 + dl;
    int l = c * 16 + ll;
    __shared__ float hpS[16][17];
    __shared__ float A2S[16][17];
    __shared__ float CsS[256];
    {
        int dd = tid >> 4, ss = tid & 15;
        hpS[dd][ss] = hst[(size_t)c * NLANE + dg * 256 + tid];
        A2S[dd][ss] = A2pre[(size_t)dg * 256 + tid];
        CsS[tid]    = x_dbl[(size_t)(c * 16 + dd) * 64 + 28 + ss];
    }
    __syncthreads();
    float Dl = Dloc[(size_t)l * DI + d];
    float y  = bf2f(ybuf[(size_t)l * DI + d]);
    float xv = bf2f(xsb[(size_t)l * DI + d]);
    float z  = xz[(size_t)l * 768 + 384 + d];
    #pragma unroll
    for (int s = 0; s < 16; ++s) {
        float e = EXP2(A2S[dl][s] * Dl);
        y = fmaf(CsS[ll * 16 + s] * e, hpS[dl][s], y);
    }
    float val = (y + xv * Dvec[d]) * siluf_(z);
    ybuf[(size_t)l * DI + d] = f2bf(val);
}

// ---- ln2 + residual, 16-token blocks, coalesced transposed store to o5[c][t][sp] ----
__global__ __launch_bounds__(256) void ln2_kernel(const float* __restrict__ tokens,
                                                  const float* __restrict__ gout,
                                                  const float* __restrict__ g,
                                                  const float* __restrict__ bb,
                                                  float* __restrict__ o5) {
    int blk = blockIdx.x;
    int t = blk >> 4, g16 = blk & 15;
    int l0 = t * 256 + g16 * 16;
    int tid = threadIdx.x;
    __shared__ float P[16 * 196];
    __shared__ float ms[16], rs[16];
    for (int e = tid; e < 3072; e += 256) {
        int w2 = e / 192, c = e - w2 * 192;
        size_t off = (size_t)(l0 + w2) * DIMC + c;
        P[w2 * 196 + c] = tokens[off] + gout[off];
    }
    __syncthreads();
    int grp = tid >> 4, ws = tid & 15;
    float s1 = 0.f, s2 = 0.f;
    #pragma unroll
    for (int k = 0; k < 12; ++k) {
        float v = P[grp * 196 + ws + 16 * k];
        s1 += v; s2 += v * v;
    }
    s1 += __shfl_xor(s1, 1); s2 += __shfl_xor(s2, 1);
    s1 += __shfl_xor(s1, 2); s2 += __shfl_xor(s2, 2);
    s1 += __shfl_xor(s1, 4); s2 += __shfl_xor(s2, 4);
    s1 += __shfl_xor(s1, 8); s2 += __shfl_xor(s2, 8);
    if (ws == 0) {
        float m = s1 * (1.f / 192.f);
        ms[grp] = m;
        rs[grp] = rsqrtf(s2 * (1.f / 192.f) - m * m + 1e-5f);
    }
    __syncthreads();
    for (int e = tid; e < 3072; e += 256) {
        int c = e >> 4, w2 = e & 15;
        float val = (P[w2 * 196 + c] - ms[w2]) * rs[w2] * g[c] + bb[c];
        o5[((size_t)c * 16 + t) * 256 + g16 * 16 + w2] = val;
    }
}

// ---- pooled mean + rfft bins 1..7 + sigmoid -> weight[c] ----
__global__ __launch_bounds__(256) void fft_kernel(const float* __restrict__ o5,
                                                  float* __restrict__ wgt) {
    int c = blockIdx.x;
    __shared__ float pooled[16];
    __shared__ float mag[8];
    int tid = threadIdx.x;
    int wv = tid >> 6, lane = tid & 63;
    for (int t = wv * 4; t < wv * 4 + 4; ++t) {
        float s = 0.f;
        #pragma unroll
        for (int r = 0; r < 4; ++r) s += o5[(size_t)c * 4096 + t * 256 + lane + r * 64];
        s += __shfl_xor(s, 1); s += __shfl_xor(s, 2); s += __shfl_xor(s, 4);
        s += __shfl_xor(s, 8); s += __shfl_xor(s, 16); s += __shfl_xor(s, 32);
        if (lane == 0) pooled[t] = s * (1.f / 256.f);
    }
    __syncthreads();
    if (tid >= 1 && tid <= 7) {
        int k = tid;
        float re = 0.f, im = 0.f;
        for (int t = 0; t < 16; ++t) {
            float ang = -0.39269908169872414f * (float)(k * t);
            re = fmaf(pooled[t], cosf(ang), re);
            im = fmaf(pooled[t], sinf(ang), im);
        }
        mag[k] = sqrtf(re * re + im * im);
    }
    __syncthreads();
    if (tid == 0) {
        float m = 0.f;
        for (int k = 1; k <= 7; ++k) m += mag[k];
        wgt[c] = sigmoidf_(m * (1.f / 7.f));
    }
}

// ---- trilinear 4x upsample, 4-wide in w ----
__global__ __launch_bounds__(256) void upsample_kernel(const float* __restrict__ o5,
                                                       const float* __restrict__ wgt,
                                                       const float* __restrict__ x,
                                                       float* __restrict__ out) {
    int idx = blockIdx.x * 256 + threadIdx.x;    // < 192*16*64*16
    int k  = idx & 15;
    int h  = (idx >> 4) & 63;
    int t  = (idx >> 10) & 15;
    int c  = idx >> 14;
    float sh = h * 0.25f - 0.375f;
    int h0 = (int)floorf(sh); float fh = sh - (float)h0;
    int h0c = min(max(h0, 0), 15), h1c = min(max(h0 + 1, 0), 15);
    const float* pl = o5 + ((size_t)c * 16 + t) * 256;
    int cm = max(k - 1, 0), cp = min(k + 1, 15);
    float r0m = pl[h0c * 16 + cm], r00 = pl[h0c * 16 + k], r0p = pl[h0c * 16 + cp];
    float r1m = pl[h1c * 16 + cm], r10 = pl[h1c * 16 + k], r1p = pl[h1c * 16 + cp];
    float gh = 1.f - fh;
    float vm = r0m * gh + r1m * fh;
    float v0 = r00 * gh + r10 * fh;
    float vp = r0p * gh + r1p * fh;
    float wc = wgt[c];
    size_t off = (size_t)idx * 4;
    float4 xv = *(const float4*)(x + off);
    float4 o;
    o.x = (vm * 0.375f + v0 * 0.625f) * wc * sigmoidf_(xv.x);
    o.y = (vm * 0.125f + v0 * 0.875f) * wc * sigmoidf_(xv.y);
    o.z = (v0 * 0.875f + vp * 0.125f) * wc * sigmoidf_(xv.z);
    o.w = (v0 * 0.625f + vp * 0.375f) * wc * sigmoidf_(xv.w);
    *(float4*)(out + off) = o;
}

extern "C" void kernel_launch(void* const* d_in, const int* in_sizes, int n_in,
                              void* d_out, int out_size, void* d_ws, size_t ws_size,
                              hipStream_t stream) {
    const float* x      = (const float*)d_in[0];
    const float* ln1_g  = (const float*)d_in[1];
    const float* ln1_b  = (const float*)d_in[2];
    const float* ln2_g  = (const float*)d_in[3];
    const float* ln2_b  = (const float*)d_in[4];
    const float* W_in   = (const float*)d_in[5];
    const float* conv_w = (const float*)d_in[6];
    const float* conv_b = (const float*)d_in[7];
    const float* W_xp   = (const float*)d_in[8];
    const float* W_dt   = (const float*)d_in[9];
    const float* b_dt   = (const float*)d_in[10];
    const float* A_log  = (const float*)d_in[11];
    const float* Dvec   = (const float*)d_in[12];
    const float* W_out  = (const float*)d_in[13];
    float* out = (float*)d_out;

    float* ws = (float*)d_ws;
    float* tokens = ws;  ws += (size_t)LTOK * DIMC;
    float* xz     = ws;  ws += (size_t)LTOK * 768;
    float* x_dbl  = ws;  ws += (size_t)LTOK * 64;
    float* chA    = ws;  ws += (size_t)NLANE * NCH;
    float* chB    = ws;  ws += (size_t)NLANE * NCH;
    float* hst    = ws;  ws += (size_t)NLANE * NCH;
    float* Dloc   = ws;  ws += (size_t)LTOK * DI;
    float* gout   = ws;  ws += (size_t)LTOK * DIMC;
    float* o5     = ws;  ws += (size_t)DIMC * LTOK;
    float* A2pre  = ws;  ws += NLANE;
    float* wgt    = ws;  ws += 256;
    unsigned short* ytok     = (unsigned short*)ws;  ws += (size_t)LTOK * DIMC / 2;
    unsigned short* ybuf     = (unsigned short*)ws;  ws += (size_t)LTOK * DI / 2;
    unsigned short* xsb      = (unsigned short*)ws;  ws += (size_t)LTOK * DI / 2;
    unsigned short* W_in_bf  = (unsigned short*)ws;  ws += (size_t)768 * 192 / 2;
    unsigned short* W_out_bf = (unsigned short*)ws;  ws += (size_t)192 * 384 / 2;
    unsigned short* W_xp_pad = (unsigned short*)ws;  ws += (size_t)64 * 384 / 2;

    poolln_kernel<<<288, 256, 0, stream>>>(x, ln1_g, ln1_b, W_in, W_out, W_xp, A_log,
                                           tokens, ytok, W_in_bf, W_out_bf, W_xp_pad, A2pre);
    gemm_mfma<192><<<dim3(12, 64), 256, 0, stream>>>(ytok, W_in_bf, xz, 768);
    convxdbl<<<256, 256, 0, stream>>>(xz, conv_w, conv_b, W_xp_pad, xsb, x_dbl);
    scan1<<<dim3(6, NCH), 256, 0, stream>>>(x_dbl, xsb, W_dt, b_dt, A2pre, chA, chB, Dloc, ybuf);
    scan2<<<NLANE / 256, 256, 0, stream>>>(chA, chB, hst);
    scan3fix<<<dim3(24, NCH), 256, 0, stream>>>(hst, Dloc, x_dbl, A2pre, xsb, xz, Dvec, ybuf);
    gemm_mfma<384><<<dim3(3, 64), 256, 0, stream>>>(ybuf, W_out_bf, gout, 192);
    ln2_kernel<<<256, 256, 0, stream>>>(tokens, gout, ln2_g, ln2_b, o5);
    fft_kernel<<<192, 256, 0, stream>>>(o5, wgt);
    upsample_kernel<<<12288, 256, 0, stream>>>(o5, wgt, x, out);
}

// Round 7
// 116.009 us; speedup vs baseline: 1.7293x; 1.0770x over previous
//
#include <hip/hip_runtime.h>
#include <math.h>

#define DIMC 192
#define DI   384
#define DS   16
#define LTOK 4096
#define NCH  256
#define CLEN 16
#define NLANE (DI*DS)   // 6144
#define L2E  1.4426950408889634f
#define LN2  0.6931471805599453f

typedef __attribute__((ext_vector_type(8))) short    bf16x8;
typedef __attribute__((ext_vector_type(8))) unsigned short u16x8;
typedef __attribute__((ext_vector_type(4))) float    f32x4;

__device__ __forceinline__ float EXP2(float x) { return __builtin_amdgcn_exp2f(x); }
__device__ __forceinline__ float RCP(float x)  { return __builtin_amdgcn_rcpf(x); }
__device__ __forceinline__ float LOG2(float x) { return __builtin_amdgcn_logf(x); }

__device__ __forceinline__ float sigmoidf_(float x) { return RCP(1.f + EXP2(-x * L2E)); }
__device__ __forceinline__ float siluf_(float x)    { return x * RCP(1.f + EXP2(-x * L2E)); }
__device__ __forceinline__ unsigned short f2bf(float f) {
    unsigned int u = __float_as_uint(f);
    u += 0x7FFFu + ((u >> 16) & 1u);
    return (unsigned short)(u >> 16);
}
__device__ __forceinline__ float bf2f(unsigned short b) {
    return __uint_as_float(((unsigned int)b) << 16);
}

// ---- fused pool+ln1 (blocks 0..255) + one-time weight prep (blocks 256..287) ----
__global__ __launch_bounds__(256) void poolln_kernel(const float* __restrict__ x,
                                                     const float* __restrict__ g,
                                                     const float* __restrict__ bb,
                                                     const float* __restrict__ W_in,
                                                     const float* __restrict__ W_out,
                                                     const float* __restrict__ W_xp,
                                                     const float* __restrict__ A_log,
                                                     float* __restrict__ tokens,
                                                     unsigned short* __restrict__ ytok,
                                                     unsigned short* __restrict__ W_in_bf,
                                                     unsigned short* __restrict__ W_out_bf,
                                                     unsigned short* __restrict__ W_xp_pad,
                                                     float* __restrict__ A2pre) {
    int blk = blockIdx.x;
    int tid = threadIdx.x;
    if (blk >= 256) {   // prep path
        int id = (blk - 256) * 256 + tid;     // 0..8191
        for (int i = id; i < 768 * 192; i += 8192) W_in_bf[i] = f2bf(W_in[i]);
        for (int i = id; i < 192 * 384; i += 8192) W_out_bf[i] = f2bf(W_out[i]);
        for (int i = id; i < 64 * 384; i += 8192) {
            int row = i / 384;
            W_xp_pad[i] = (row < 44) ? f2bf(W_xp[i]) : (unsigned short)0;
        }
        for (int i = id; i < NLANE; i += 8192) A2pre[i] = -expf(A_log[i]) * L2E;
        return;
    }
    int t = blk >> 4, hs = blk & 15;
    int grp = tid >> 4, ws = tid & 15;
    __shared__ float P[16 * 196];
    __shared__ float ms[16], rs[16];
    #pragma unroll
    for (int k = 0; k < 12; ++k) {
        int c = grp + (k << 4);
        const float* base = x + ((size_t)(c * 16 + t) * 64 + hs * 4) * 64 + ws * 4;
        float s = 0.f;
        #pragma unroll
        for (int i = 0; i < 4; ++i) {
            float4 v = *(const float4*)(base + i * 64);
            s += v.x + v.y + v.z + v.w;
        }
        P[ws * 196 + c] = s * 0.0625f;
    }
    __syncthreads();
    float s1 = 0.f, s2 = 0.f;
    #pragma unroll
    for (int k = 0; k < 12; ++k) {
        float v = P[grp * 196 + ws + 16 * k];
        s1 += v; s2 += v * v;
    }
    s1 += __shfl_xor(s1, 1); s2 += __shfl_xor(s2, 1);
    s1 += __shfl_xor(s1, 2); s2 += __shfl_xor(s2, 2);
    s1 += __shfl_xor(s1, 4); s2 += __shfl_xor(s2, 4);
    s1 += __shfl_xor(s1, 8); s2 += __shfl_xor(s2, 8);
    if (ws == 0) {
        float m = s1 * (1.f / 192.f);
        ms[grp] = m;
        rs[grp] = rsqrtf(s2 * (1.f / 192.f) - m * m + 1e-5f);
    }
    __syncthreads();
    int l0 = t * 256 + hs * 16;
    for (int e = tid; e < 16 * 192; e += 256) {
        int w2 = e / 192, c = e - w2 * 192;
        float v = P[w2 * 196 + c];
        float val = (v - ms[w2]) * rs[w2] * g[c] + bb[c];
        tokens[(size_t)(l0 + w2) * DIMC + c] = v;
        ytok[(size_t)(l0 + w2) * DIMC + c] = f2bf(val);
    }
}

// ---- MFMA GEMM: C[m][n] = sum_k A_bf16[m][k] * W_bf16[n][k], K tiled by 192 ----
template<int K>
__global__ __launch_bounds__(256) void gemm_mfma(const unsigned short* __restrict__ A,
                                                 const unsigned short* __restrict__ Wb,
                                                 float* __restrict__ Cout,
                                                 int N) {
    constexpr int KT = 192;
    constexpr int KP = KT + 8;
    __shared__ unsigned short As[64 * KP];
    __shared__ unsigned short Bs[64 * KP];
    int bm = blockIdx.y * 64;
    int bn = blockIdx.x * 64;
    int tid = threadIdx.x;
    int lane = tid & 63, w = tid >> 6;
    int wr = w >> 1, wc = w & 1;
    int r16 = lane & 15, h = lane >> 4;
    f32x4 acc[2][2] = {};
    for (int kt = 0; kt < K; kt += KT) {
        for (int c = tid; c < 64 * (KT / 8); c += 256) {
            int row = c / (KT / 8), col = (c % (KT / 8)) * 8;
            *(u16x8*)&As[row * KP + col] = *(const u16x8*)(A + (size_t)(bm + row) * K + kt + col);
            *(u16x8*)&Bs[row * KP + col] = *(const u16x8*)(Wb + (size_t)(bn + row) * K + kt + col);
        }
        __syncthreads();
        #pragma unroll
        for (int k0 = 0; k0 < KT; k0 += 32) {
            bf16x8 a0 = *(const bf16x8*)&As[(wr * 32 + r16)      * KP + k0 + 8 * h];
            bf16x8 a1 = *(const bf16x8*)&As[(wr * 32 + 16 + r16) * KP + k0 + 8 * h];
            bf16x8 b0 = *(const bf16x8*)&Bs[(wc * 32 + r16)      * KP + k0 + 8 * h];
            bf16x8 b1 = *(const bf16x8*)&Bs[(wc * 32 + 16 + r16) * KP + k0 + 8 * h];
            acc[0][0] = __builtin_amdgcn_mfma_f32_16x16x32_bf16(a0, b0, acc[0][0], 0, 0, 0);
            acc[0][1] = __builtin_amdgcn_mfma_f32_16x16x32_bf16(a0, b1, acc[0][1], 0, 0, 0);
            acc[1][0] = __builtin_amdgcn_mfma_f32_16x16x32_bf16(a1, b0, acc[1][0], 0, 0, 0);
            acc[1][1] = __builtin_amdgcn_mfma_f32_16x16x32_bf16(a1, b1, acc[1][1], 0, 0, 0);
        }
        __syncthreads();
    }
    #pragma unroll
    for (int fm = 0; fm < 2; ++fm)
        #pragma unroll
        for (int fn = 0; fn < 2; ++fn)
            #pragma unroll
            for (int i = 0; i < 4; ++i) {
                int r = bm + wr * 32 + fm * 16 + h * 4 + i;
                int cc = bn + wc * 32 + fn * 16 + r16;
                Cout[(size_t)r * N + cc] = acc[fm][fn][i];
            }
}

// ---- conv(k=4 causal)+silu -> xsb, then MFMA x_dbl = xs @ W_xp_pad^T (N=64) ----
__global__ __launch_bounds__(256) void convxdbl(const float* __restrict__ xz,
                                                const float* __restrict__ conv_w,
                                                const float* __restrict__ conv_b,
                                                const unsigned short* __restrict__ Wxp,
                                                unsigned short* __restrict__ xsb,
                                                float* __restrict__ x_dbl) {
    int l0 = blockIdx.x * 16;
    int tid = threadIdx.x;
    __shared__ unsigned short As[16 * 392];
    __shared__ float xd[16 * 64];
    for (int e = tid * 2; e < 16 * 384; e += 512) {
        int row = e / 384, d = e - row * 384;
        int l = l0 + row;
        float ax = conv_b[d], ay = conv_b[d + 1];
        #pragma unroll
        for (int k = 0; k < 4; ++k) {
            int ll = l - 3 + k;
            if (ll >= 0) {
                float2 v = *(const float2*)(xz + (size_t)ll * 768 + d);
                ax = fmaf(conv_w[d * 4 + k],       v.x, ax);
                ay = fmaf(conv_w[(d + 1) * 4 + k], v.y, ay);
            }
        }
        ushort2 b2;
        b2.x = f2bf(siluf_(ax));
        b2.y = f2bf(siluf_(ay));
        *(ushort2*)&As[row * 392 + d] = b2;
        *(ushort2*)(xsb + (size_t)l * 384 + d) = b2;
    }
    __syncthreads();
    int lane = tid & 63, w = tid >> 6;
    int r16 = lane & 15, hh = lane >> 4;
    f32x4 acc = {};
    #pragma unroll
    for (int k0 = 0; k0 < 384; k0 += 32) {
        bf16x8 a = *(const bf16x8*)&As[r16 * 392 + k0 + 8 * hh];
        bf16x8 b = *(const bf16x8*)(Wxp + (size_t)(w * 16 + r16) * 384 + k0 + 8 * hh);
        acc = __builtin_amdgcn_mfma_f32_16x16x32_bf16(a, b, acc, 0, 0, 0);
    }
    #pragma unroll
    for (int i = 0; i < 4; ++i) xd[(hh * 4 + i) * 64 + w * 16 + r16] = acc[i];
    __syncthreads();
    {
        int e = tid * 4;
        int row = e >> 6, col = e & 63;
        *(float4*)(x_dbl + (size_t)(l0 + row) * 64 + col) = *(const float4*)&xd[e];
    }
}

// ---- scan1: compute dt in-block from x_dbl; local scan + y_local + Dloc + summaries ----
__global__ __launch_bounds__(256) void scan1(const float* __restrict__ x_dbl,
                                             const unsigned short* __restrict__ xsb,
                                             const float* __restrict__ W_dt,
                                             const float* __restrict__ b_dt,
                                             const float* __restrict__ A2pre,
                                             float* __restrict__ chA,
                                             float* __restrict__ chB,
                                             float* __restrict__ Dloc,
                                             unsigned short* __restrict__ yloc) {
    int tid = threadIdx.x;
    int dg = blockIdx.x;          // 0..5
    int c  = blockIdx.y;          // 0..NCH-1
    __shared__ float xdblS[16 * 48];
    __shared__ float wdtS[64 * 13];
    __shared__ float dtS[16][64];
    __shared__ unsigned short xsS[16][64];
    for (int i = tid; i < 768; i += 256) {
        int row = i / 48, col = i - row * 48;
        xdblS[i] = x_dbl[(size_t)(c * 16 + row) * 64 + col];
    }
    for (int i = tid; i < 768; i += 256) {
        int dl_ = i / 12, r = i - dl_ * 12;
        wdtS[dl_ * 13 + r] = W_dt[(size_t)dg * 768 + i];
    }
    for (int i = tid; i < 1024; i += 256) {
        int row = i >> 6, dl_ = i & 63;
        xsS[row][dl_] = xsb[(size_t)(c * 16 + row) * 384 + dg * 64 + dl_];
    }
    __syncthreads();
    {
        int dl_ = tid & 63;
        float bd = b_dt[dg * 64 + dl_];
        #pragma unroll
        for (int i2 = 0; i2 < 4; ++i2) {
            int row = (tid >> 6) + 4 * i2;
            float s = bd;
            #pragma unroll
            for (int r = 0; r < 12; ++r)
                s = fmaf(xdblS[row * 48 + r], wdtS[dl_ * 13 + r], s);
            dtS[row][dl_] = (s > 20.f) ? s : LOG2(1.f + EXP2(s * L2E)) * LN2;
        }
    }
    __syncthreads();
    int sq = tid & 3, dl = tid >> 2;
    int d = dg * 64 + dl;
    float4 a4 = *(const float4*)(A2pre + (size_t)d * DS + sq * 4);
    float A2[4] = {a4.x, a4.y, a4.z, a4.w};
    float h[4] = {};
    float dts = 0.f;
    #pragma unroll
    for (int i = 0; i < CLEN; ++i) {
        int l = c * CLEN + i;
        float dtv = dtS[i][dl];
        float xv  = bf2f(xsS[i][dl]);
        float dtx = dtv * xv;
        dts += dtv;
        float y = 0.f;
        #pragma unroll
        for (int u = 0; u < 4; ++u) {
            float a = EXP2(dtv * A2[u]);
            h[u] = fmaf(a, h[u], dtx * xdblS[i * 48 + 12 + sq * 4 + u]);
            y = fmaf(h[u], xdblS[i * 48 + 28 + sq * 4 + u], y);
        }
        y += __shfl_xor(y, 1);
        y += __shfl_xor(y, 2);
        if (sq == 0) {
            yloc[(size_t)l * DI + d] = f2bf(y);
            Dloc[(size_t)l * DI + d] = dts;
        }
    }
    size_t base = (size_t)c * NLANE + d * DS + sq * 4;
    float4 pa, pb;
    pa.x = EXP2(dts * A2[0]); pa.y = EXP2(dts * A2[1]);
    pa.z = EXP2(dts * A2[2]); pa.w = EXP2(dts * A2[3]);
    pb.x = h[0]; pb.y = h[1]; pb.z = h[2]; pb.w = h[3];
    *(float4*)&chA[base] = pa;
    *(float4*)&chB[base] = pb;
}

// ---- scan2p: hierarchical parallel inter-chunk scan ----
// block 256 = (g 16) x (ll 16); grid NLANE/16 = 384. Thread owns 16 chunks of one lane.
__global__ __launch_bounds__(256) void scan2p(const float* __restrict__ chA,
                                              const float* __restrict__ chB,
                                              float* __restrict__ hst) {
    int tid = threadIdx.x;
    int ll = tid & 15;
    int g  = tid >> 4;
    int lane = blockIdx.x * 16 + ll;
    float a[16], b[16];
    #pragma unroll
    for (int i = 0; i < 16; ++i) {
        int c = g * 16 + i;
        a[i] = chA[(size_t)c * NLANE + lane];
        b[i] = chB[(size_t)c * NLANE + lane];
    }
    // thread-local combine (h_out = Ath*h_in + Bth)
    float Ath = 1.f, Bth = 0.f;
    #pragma unroll
    for (int i = 0; i < 16; ++i) {
        Bth = fmaf(a[i], Bth, b[i]);
        Ath *= a[i];
    }
    __shared__ float sA[16][17], sB[16][17];
    sA[g][ll] = Ath; sB[g][ll] = Bth;
    __syncthreads();
    // Hillis-Steele inclusive scan over g (composition: comb(prev, cur))
    #pragma unroll
    for (int step = 1; step < 16; step <<= 1) {
        float pA = 1.f, pB = 0.f;
        if (g >= step) { pA = sA[g - step][ll]; pB = sB[g - step][ll]; }
        __syncthreads();
        if (g >= step) {
            float cA = sA[g][ll], cB = sB[g][ll];
            sA[g][ll] = cA * pA;
            sB[g][ll] = fmaf(cA, pB, cB);
        }
        __syncthreads();
    }
    float h = (g == 0) ? 0.f : sB[g - 1][ll];   // h0 = 0 -> prefix state = B
    #pragma unroll
    for (int i = 0; i < 16; ++i) {
        int c = g * 16 + i;
        hst[(size_t)c * NLANE + lane] = h;
        h = fmaf(a[i], h, b[i]);
    }
}

// scan3fix: elementwise fix-up + gate. block 256 = 16 l x 16 d; grid (24, NCH)
__global__ __launch_bounds__(256) void scan3fix(const float* __restrict__ hst,
                                                const float* __restrict__ Dloc,
                                                const float* __restrict__ x_dbl,
                                                const float* __restrict__ A2pre,
                                                const unsigned short* __restrict__ xsb,
                                                const float* __restrict__ xz,
                                                const float* __restrict__ Dvec,
                                                unsigned short* __restrict__ ybuf) {
    int dg = blockIdx.x;        // 0..23
    int c  = blockIdx.y;        // 0..NCH-1
    int tid = threadIdx.x;
    int ll = tid >> 4, dl = tid & 15;
    int d = dg * 16 + dl;
    int l = c * 16 + ll;
    __shared__ float hpS[16][17];
    __shared__ float A2S[16][17];
    __shared__ float CsS[256];
    {
        int dd = tid >> 4, ss = tid & 15;
        hpS[dd][ss] = hst[(size_t)c * NLANE + dg * 256 + tid];
        A2S[dd][ss] = A2pre[(size_t)dg * 256 + tid];
        CsS[tid]    = x_dbl[(size_t)(c * 16 + dd) * 64 + 28 + ss];
    }
    __syncthreads();
    float Dl = Dloc[(size_t)l * DI + d];
    float y  = bf2f(ybuf[(size_t)l * DI + d]);
    float xv = bf2f(xsb[(size_t)l * DI + d]);
    float z  = xz[(size_t)l * 768 + 384 + d];
    #pragma unroll
    for (int s = 0; s < 16; ++s) {
        float e = EXP2(A2S[dl][s] * Dl);
        y = fmaf(CsS[ll * 16 + s] * e, hpS[dl][s], y);
    }
    float val = (y + xv * Dvec[d]) * siluf_(z);
    ybuf[(size_t)l * DI + d] = f2bf(val);
}

// ---- ln2 + residual, 16-token blocks, coalesced transposed store to o5[c][t][sp] ----
__global__ __launch_bounds__(256) void ln2_kernel(const float* __restrict__ tokens,
                                                  const float* __restrict__ gout,
                                                  const float* __restrict__ g,
                                                  const float* __restrict__ bb,
                                                  float* __restrict__ o5) {
    int blk = blockIdx.x;
    int t = blk >> 4, g16 = blk & 15;
    int l0 = t * 256 + g16 * 16;
    int tid = threadIdx.x;
    __shared__ float P[16 * 196];
    __shared__ float ms[16], rs[16];
    for (int e = tid; e < 3072; e += 256) {
        int w2 = e / 192, c = e - w2 * 192;
        size_t off = (size_t)(l0 + w2) * DIMC + c;
        P[w2 * 196 + c] = tokens[off] + gout[off];
    }
    __syncthreads();
    int grp = tid >> 4, ws = tid & 15;
    float s1 = 0.f, s2 = 0.f;
    #pragma unroll
    for (int k = 0; k < 12; ++k) {
        float v = P[grp * 196 + ws + 16 * k];
        s1 += v; s2 += v * v;
    }
    s1 += __shfl_xor(s1, 1); s2 += __shfl_xor(s2, 1);
    s1 += __shfl_xor(s1, 2); s2 += __shfl_xor(s2, 2);
    s1 += __shfl_xor(s1, 4); s2 += __shfl_xor(s2, 4);
    s1 += __shfl_xor(s1, 8); s2 += __shfl_xor(s2, 8);
    if (ws == 0) {
        float m = s1 * (1.f / 192.f);
        ms[grp] = m;
        rs[grp] = rsqrtf(s2 * (1.f / 192.f) - m * m + 1e-5f);
    }
    __syncthreads();
    for (int e = tid; e < 3072; e += 256) {
        int c = e >> 4, w2 = e & 15;
        float val = (P[w2 * 196 + c] - ms[w2]) * rs[w2] * g[c] + bb[c];
        o5[((size_t)c * 16 + t) * 256 + g16 * 16 + w2] = val;
    }
}

// ---- pooled mean + rfft bins 1..7 + sigmoid -> weight[c] ----
__global__ __launch_bounds__(256) void fft_kernel(const float* __restrict__ o5,
                                                  float* __restrict__ wgt) {
    int c = blockIdx.x;
    __shared__ float pooled[16];
    __shared__ float mag[8];
    int tid = threadIdx.x;
    int wv = tid >> 6, lane = tid & 63;
    for (int t = wv * 4; t < wv * 4 + 4; ++t) {
        float s = 0.f;
        #pragma unroll
        for (int r = 0; r < 4; ++r) s += o5[(size_t)c * 4096 + t * 256 + lane + r * 64];
        s += __shfl_xor(s, 1); s += __shfl_xor(s, 2); s += __shfl_xor(s, 4);
        s += __shfl_xor(s, 8); s += __shfl_xor(s, 16); s += __shfl_xor(s, 32);
        if (lane == 0) pooled[t] = s * (1.f / 256.f);
    }
    __syncthreads();
    if (tid >= 1 && tid <= 7) {
        int k = tid;
        float re = 0.f, im = 0.f;
        for (int t = 0; t < 16; ++t) {
            float ang = -0.39269908169872414f * (float)(k * t);
            re = fmaf(pooled[t], cosf(ang), re);
            im = fmaf(pooled[t], sinf(ang), im);
        }
        mag[k] = sqrtf(re * re + im * im);
    }
    __syncthreads();
    if (tid == 0) {
        float m = 0.f;
        for (int k = 1; k <= 7; ++k) m += mag[k];
        wgt[c] = sigmoidf_(m * (1.f / 7.f));
    }
}

// ---- trilinear 4x upsample, 4-wide in w ----
__global__ __launch_bounds__(256) void upsample_kernel(const float* __restrict__ o5,
                                                       const float* __restrict__ wgt,
                                                       const float* __restrict__ x,
                                                       float* __restrict__ out) {
    int idx = blockIdx.x * 256 + threadIdx.x;    // < 192*16*64*16
    int k  = idx & 15;
    int h  = (idx >> 4) & 63;
    int t  = (idx >> 10) & 15;
    int c  = idx >> 14;
    float sh = h * 0.25f - 0.375f;
    int h0 = (int)floorf(sh); float fh = sh - (float)h0;
    int h0c = min(max(h0, 0), 15), h1c = min(max(h0 + 1, 0), 15);
    const float* pl = o5 + ((size_t)c * 16 + t) * 256;
    int cm = max(k - 1, 0), cp = min(k + 1, 15);
    float r0m = pl[h0c * 16 + cm], r00 = pl[h0c * 16 + k], r0p = pl[h0c * 16 + cp];
    float r1m = pl[h1c * 16 + cm], r10 = pl[h1c * 16 + k], r1p = pl[h1c * 16 + cp];
    float gh = 1.f - fh;
    float vm = r0m * gh + r1m * fh;
    float v0 = r00 * gh + r10 * fh;
    float vp = r0p * gh + r1p * fh;
    float wc = wgt[c];
    size_t off = (size_t)idx * 4;
    float4 xv = *(const float4*)(x + off);
    float4 o;
    o.x = (vm * 0.375f + v0 * 0.625f) * wc * sigmoidf_(xv.x);
    o.y = (vm * 0.125f + v0 * 0.875f) * wc * sigmoidf_(xv.y);
    o.z = (v0 * 0.875f + vp * 0.125f) * wc * sigmoidf_(xv.z);
    o.w = (v0 * 0.625f + vp * 0.375f) * wc * sigmoidf_(xv.w);
    *(float4*)(out + off) = o;
}

extern "C" void kernel_launch(void* const* d_in, const int* in_sizes, int n_in,
                              void* d_out, int out_size, void* d_ws, size_t ws_size,
                              hipStream_t stream) {
    const float* x      = (const float*)d_in[0];
    const float* ln1_g  = (const float*)d_in[1];
    const float* ln1_b  = (const float*)d_in[2];
    const float* ln2_g  = (const float*)d_in[3];
    const float* ln2_b  = (const float*)d_in[4];
    const float* W_in   = (const float*)d_in[5];
    const float* conv_w = (const float*)d_in[6];
    const float* conv_b = (const float*)d_in[7];
    const float* W_xp   = (const float*)d_in[8];
    const float* W_dt   = (const float*)d_in[9];
    const float* b_dt   = (const float*)d_in[10];
    const float* A_log  = (const float*)d_in[11];
    const float* Dvec   = (const float*)d_in[12];
    const float* W_out  = (const float*)d_in[13];
    float* out = (float*)d_out;

    float* ws = (float*)d_ws;
    float* tokens = ws;  ws += (size_t)LTOK * DIMC;
    float* xz     = ws;  ws += (size_t)LTOK * 768;
    float* x_dbl  = ws;  ws += (size_t)LTOK * 64;
    float* chA    = ws;  ws += (size_t)NLANE * NCH;
    float* chB    = ws;  ws += (size_t)NLANE * NCH;
    float* hst    = ws;  ws += (size_t)NLANE * NCH;
    float* Dloc   = ws;  ws += (size_t)LTOK * DI;
    float* gout   = ws;  ws += (size_t)LTOK * DIMC;
    float* o5     = ws;  ws += (size_t)DIMC * LTOK;
    float* A2pre  = ws;  ws += NLANE;
    float* wgt    = ws;  ws += 256;
    unsigned short* ytok     = (unsigned short*)ws;  ws += (size_t)LTOK * DIMC / 2;
    unsigned short* ybuf     = (unsigned short*)ws;  ws += (size_t)LTOK * DI / 2;
    unsigned short* xsb      = (unsigned short*)ws;  ws += (size_t)LTOK * DI / 2;
    unsigned short* W_in_bf  = (unsigned short*)ws;  ws += (size_t)768 * 192 / 2;
    unsigned short* W_out_bf = (unsigned short*)ws;  ws += (size_t)192 * 384 / 2;
    unsigned short* W_xp_pad = (unsigned short*)ws;  ws += (size_t)64 * 384 / 2;

    poolln_kernel<<<288, 256, 0, stream>>>(x, ln1_g, ln1_b, W_in, W_out, W_xp, A_log,
                                           tokens, ytok, W_in_bf, W_out_bf, W_xp_pad, A2pre);
    gemm_mfma<192><<<dim3(12, 64), 256, 0, stream>>>(ytok, W_in_bf, xz, 768);
    convxdbl<<<256, 256, 0, stream>>>(xz, conv_w, conv_b, W_xp_pad, xsb, x_dbl);
    scan1<<<dim3(6, NCH), 256, 0, stream>>>(x_dbl, xsb, W_dt, b_dt, A2pre, chA, chB, Dloc, ybuf);
    scan2p<<<NLANE / 16, 256, 0, stream>>>(chA, chB, hst);
    scan3fix<<<dim3(24, NCH), 256, 0, stream>>>(hst, Dloc, x_dbl, A2pre, xsb, xz, Dvec, ybuf);
    gemm_mfma<384><<<dim3(3, 64), 256, 0, stream>>>(ybuf, W_out_bf, gout, 192);
    ln2_kernel<<<256, 256, 0, stream>>>(tokens, gout, ln2_g, ln2_b, o5);
    fft_kernel<<<192, 256, 0, stream>>>(o5, wgt);
    upsample_kernel<<<12288, 256, 0, stream>>>(o5, wgt, x, out);
}

// Round 8
// 112.912 us; speedup vs baseline: 1.7767x; 1.0274x over previous
//
#include <hip/hip_runtime.h>
#include <math.h>

#define DIMC 192
#define DI   384
#define DS   16
#define LTOK 4096
#define NCH  256
#define CLEN 16
#define NLANE (DI*DS)   // 6144
#define L2E  1.4426950408889634f
#define LN2  0.6931471805599453f

typedef __attribute__((ext_vector_type(8))) short    bf16x8;
typedef __attribute__((ext_vector_type(8))) unsigned short u16x8;
typedef __attribute__((ext_vector_type(4))) float    f32x4;

__device__ __forceinline__ float EXP2(float x) { return __builtin_amdgcn_exp2f(x); }
__device__ __forceinline__ float RCP(float x)  { return __builtin_amdgcn_rcpf(x); }
__device__ __forceinline__ float LOG2(float x) { return __builtin_amdgcn_logf(x); }

__device__ __forceinline__ float sigmoidf_(float x) { return RCP(1.f + EXP2(-x * L2E)); }
__device__ __forceinline__ float siluf_(float x)    { return x * RCP(1.f + EXP2(-x * L2E)); }
__device__ __forceinline__ unsigned short f2bf(float f) {
    unsigned int u = __float_as_uint(f);
    u += 0x7FFFu + ((u >> 16) & 1u);
    return (unsigned short)(u >> 16);
}
__device__ __forceinline__ float bf2f(unsigned short b) {
    return __uint_as_float(((unsigned int)b) << 16);
}

// ---- fused pool+ln1 (blocks 0..255) + one-time weight prep (blocks 256..287) ----
__global__ __launch_bounds__(256) void poolln_kernel(const float* __restrict__ x,
                                                     const float* __restrict__ g,
                                                     const float* __restrict__ bb,
                                                     const float* __restrict__ W_in,
                                                     const float* __restrict__ W_out,
                                                     const float* __restrict__ W_xp,
                                                     const float* __restrict__ A_log,
                                                     float* __restrict__ tokens,
                                                     unsigned short* __restrict__ ytok,
                                                     unsigned short* __restrict__ W_in_bf,
                                                     unsigned short* __restrict__ W_out_bf,
                                                     unsigned short* __restrict__ W_xp_pad,
                                                     float* __restrict__ A2pre) {
    int blk = blockIdx.x;
    int tid = threadIdx.x;
    if (blk >= 256) {   // prep path
        int id = (blk - 256) * 256 + tid;     // 0..8191
        for (int i = id; i < 768 * 192; i += 8192) W_in_bf[i] = f2bf(W_in[i]);
        for (int i = id; i < 192 * 384; i += 8192) W_out_bf[i] = f2bf(W_out[i]);
        for (int i = id; i < 64 * 384; i += 8192) {
            int row = i / 384;
            W_xp_pad[i] = (row < 44) ? f2bf(W_xp[i]) : (unsigned short)0;
        }
        for (int i = id; i < NLANE; i += 8192) A2pre[i] = -expf(A_log[i]) * L2E;
        return;
    }
    int t = blk >> 4, hs = blk & 15;
    int grp = tid >> 4, ws = tid & 15;
    __shared__ float P[16 * 196];
    __shared__ float ms[16], rs[16];
    #pragma unroll
    for (int k = 0; k < 12; ++k) {
        int c = grp + (k << 4);
        const float* base = x + ((size_t)(c * 16 + t) * 64 + hs * 4) * 64 + ws * 4;
        float s = 0.f;
        #pragma unroll
        for (int i = 0; i < 4; ++i) {
            float4 v = *(const float4*)(base + i * 64);
            s += v.x + v.y + v.z + v.w;
        }
        P[ws * 196 + c] = s * 0.0625f;
    }
    __syncthreads();
    float s1 = 0.f, s2 = 0.f;
    #pragma unroll
    for (int k = 0; k < 12; ++k) {
        float v = P[grp * 196 + ws + 16 * k];
        s1 += v; s2 += v * v;
    }
    s1 += __shfl_xor(s1, 1); s2 += __shfl_xor(s2, 1);
    s1 += __shfl_xor(s1, 2); s2 += __shfl_xor(s2, 2);
    s1 += __shfl_xor(s1, 4); s2 += __shfl_xor(s2, 4);
    s1 += __shfl_xor(s1, 8); s2 += __shfl_xor(s2, 8);
    if (ws == 0) {
        float m = s1 * (1.f / 192.f);
        ms[grp] = m;
        rs[grp] = rsqrtf(s2 * (1.f / 192.f) - m * m + 1e-5f);
    }
    __syncthreads();
    int l0 = t * 256 + hs * 16;
    for (int e = tid; e < 16 * 192; e += 256) {
        int w2 = e / 192, c = e - w2 * 192;
        float v = P[w2 * 196 + c];
        float val = (v - ms[w2]) * rs[w2] * g[c] + bb[c];
        tokens[(size_t)(l0 + w2) * DIMC + c] = v;
        ytok[(size_t)(l0 + w2) * DIMC + c] = f2bf(val);
    }
}

// ---- MFMA GEMM (xz = ytok @ W_in^T): 64x64 tiles, K=192 single-stage ----
template<int K>
__global__ __launch_bounds__(256) void gemm_mfma(const unsigned short* __restrict__ A,
                                                 const unsigned short* __restrict__ Wb,
                                                 float* __restrict__ Cout,
                                                 int N) {
    constexpr int KT = 192;
    constexpr int KP = KT + 8;
    __shared__ unsigned short As[64 * KP];
    __shared__ unsigned short Bs[64 * KP];
    int bm = blockIdx.y * 64;
    int bn = blockIdx.x * 64;
    int tid = threadIdx.x;
    int lane = tid & 63, w = tid >> 6;
    int wr = w >> 1, wc = w & 1;
    int r16 = lane & 15, h = lane >> 4;
    f32x4 acc[2][2] = {};
    for (int kt = 0; kt < K; kt += KT) {
        for (int c = tid; c < 64 * (KT / 8); c += 256) {
            int row = c / (KT / 8), col = (c % (KT / 8)) * 8;
            *(u16x8*)&As[row * KP + col] = *(const u16x8*)(A + (size_t)(bm + row) * K + kt + col);
            *(u16x8*)&Bs[row * KP + col] = *(const u16x8*)(Wb + (size_t)(bn + row) * K + kt + col);
        }
        __syncthreads();
        #pragma unroll
        for (int k0 = 0; k0 < KT; k0 += 32) {
            bf16x8 a0 = *(const bf16x8*)&As[(wr * 32 + r16)      * KP + k0 + 8 * h];
            bf16x8 a1 = *(const bf16x8*)&As[(wr * 32 + 16 + r16) * KP + k0 + 8 * h];
            bf16x8 b0 = *(const bf16x8*)&Bs[(wc * 32 + r16)      * KP + k0 + 8 * h];
            bf16x8 b1 = *(const bf16x8*)&Bs[(wc * 32 + 16 + r16) * KP + k0 + 8 * h];
            acc[0][0] = __builtin_amdgcn_mfma_f32_16x16x32_bf16(a0, b0, acc[0][0], 0, 0, 0);
            acc[0][1] = __builtin_amdgcn_mfma_f32_16x16x32_bf16(a0, b1, acc[0][1], 0, 0, 0);
            acc[1][0] = __builtin_amdgcn_mfma_f32_16x16x32_bf16(a1, b0, acc[1][0], 0, 0, 0);
            acc[1][1] = __builtin_amdgcn_mfma_f32_16x16x32_bf16(a1, b1, acc[1][1], 0, 0, 0);
        }
        __syncthreads();
    }
    #pragma unroll
    for (int fm = 0; fm < 2; ++fm)
        #pragma unroll
        for (int fn = 0; fn < 2; ++fn)
            #pragma unroll
            for (int i = 0; i < 4; ++i) {
                int r = bm + wr * 32 + fm * 16 + h * 4 + i;
                int cc = bn + wc * 32 + fn * 16 + r16;
                Cout[(size_t)r * N + cc] = acc[fm][fn][i];
            }
}

// ---- convscan: conv+silu -> LDS, x_dbl MFMA -> LDS, dt + local scan (h[16]/thread) ----
// grid 256 chunks, 384 threads (thread = d channel)
__global__ __launch_bounds__(384) void convscan(const float* __restrict__ xz,
                                                const float* __restrict__ conv_w,
                                                const float* __restrict__ conv_b,
                                                const unsigned short* __restrict__ Wxp,
                                                const float* __restrict__ W_dt,
                                                const float* __restrict__ b_dt,
                                                const float* __restrict__ A2pre,
                                                unsigned short* __restrict__ xsb,
                                                float* __restrict__ x_dbl,
                                                float* __restrict__ chA,
                                                float* __restrict__ chB,
                                                float* __restrict__ Dloc,
                                                unsigned short* __restrict__ yloc) {
    int c = blockIdx.x;
    int l0 = c * CLEN;
    int tid = threadIdx.x;        // = d
    __shared__ unsigned short As[16 * 392];
    __shared__ float xd[16 * 64];
    {   // conv + silu, sliding window over 19 rows
        int d = tid;
        float cw0 = conv_w[d * 4 + 0], cw1 = conv_w[d * 4 + 1];
        float cw2 = conv_w[d * 4 + 2], cw3 = conv_w[d * 4 + 3];
        float cb = conv_b[d];
        float xv[19];
        #pragma unroll
        for (int j = 0; j < 19; ++j) {
            int ll = l0 - 3 + j;
            xv[j] = (ll >= 0) ? xz[(size_t)ll * 768 + d] : 0.f;
        }
        #pragma unroll
        for (int i = 0; i < 16; ++i) {
            float a = cb;
            a = fmaf(cw0, xv[i], a);
            a = fmaf(cw1, xv[i + 1], a);
            a = fmaf(cw2, xv[i + 2], a);
            a = fmaf(cw3, xv[i + 3], a);
            As[i * 392 + d] = f2bf(siluf_(a));
        }
    }
    __syncthreads();
    // coalesced xsb store
    #pragma unroll
    for (int k = 0; k < 16; ++k)
        xsb[(size_t)(l0 + k) * DI + tid] = As[k * 392 + tid];
    // x_dbl = xs @ Wxp^T  (16x64), waves 0..3
    if (tid < 256) {
        int lane = tid & 63, w = tid >> 6;
        int r16 = lane & 15, hh = lane >> 4;
        f32x4 acc = {};
        #pragma unroll
        for (int k0 = 0; k0 < 384; k0 += 32) {
            bf16x8 a = *(const bf16x8*)&As[r16 * 392 + k0 + 8 * hh];
            bf16x8 b = *(const bf16x8*)(Wxp + (size_t)(w * 16 + r16) * 384 + k0 + 8 * hh);
            acc = __builtin_amdgcn_mfma_f32_16x16x32_bf16(a, b, acc, 0, 0, 0);
        }
        #pragma unroll
        for (int i = 0; i < 4; ++i) xd[(hh * 4 + i) * 64 + w * 16 + r16] = acc[i];
    }
    __syncthreads();
    if (tid < 256) {   // persist x_dbl for scan3fix's C reads
        int row = tid >> 6, col = (tid & 63) * 4;
        *(float4*)(x_dbl + (size_t)(l0 + row) * 64 + col) = *(const float4*)&xd[row * 64 + col];
        *(float4*)(x_dbl + (size_t)(l0 + 4 + row) * 64 + col) = *(const float4*)&xd[(4 + row) * 64 + col];
        *(float4*)(x_dbl + (size_t)(l0 + 8 + row) * 64 + col) = *(const float4*)&xd[(8 + row) * 64 + col];
        *(float4*)(x_dbl + (size_t)(l0 + 12 + row) * 64 + col) = *(const float4*)&xd[(12 + row) * 64 + col];
    }
    // dt + local scan, h[16] in registers
    int d = tid;
    float wdt[12];
    #pragma unroll
    for (int r = 0; r < 12; ++r) wdt[r] = W_dt[d * 12 + r];
    float bd = b_dt[d];
    float A2[16];
    #pragma unroll
    for (int s = 0; s < 16; s += 4) {
        float4 a4 = *(const float4*)(A2pre + (size_t)d * DS + s);
        A2[s] = a4.x; A2[s + 1] = a4.y; A2[s + 2] = a4.z; A2[s + 3] = a4.w;
    }
    float h[16] = {};
    float dts = 0.f;
    #pragma unroll
    for (int i = 0; i < CLEN; ++i) {
        float sdt = bd;
        #pragma unroll
        for (int r = 0; r < 12; ++r) sdt = fmaf(xd[i * 64 + r], wdt[r], sdt);
        float dtv = (sdt > 20.f) ? sdt : LOG2(1.f + EXP2(sdt * L2E)) * LN2;
        float xvv = bf2f(As[i * 392 + d]);
        float dtx = dtv * xvv;
        dts += dtv;
        float y = 0.f;
        #pragma unroll
        for (int s = 0; s < 16; ++s) {
            float a = EXP2(dtv * A2[s]);
            h[s] = fmaf(a, h[s], dtx * xd[i * 64 + 12 + s]);
            y = fmaf(h[s], xd[i * 64 + 28 + s], y);
        }
        int l = l0 + i;
        yloc[(size_t)l * DI + d] = f2bf(y);
        Dloc[(size_t)l * DI + d] = dts;
    }
    size_t base = (size_t)c * NLANE + d * DS;
    #pragma unroll
    for (int s = 0; s < 16; s += 4) {
        float4 pa, pb;
        pa.x = EXP2(dts * A2[s + 0]); pa.y = EXP2(dts * A2[s + 1]);
        pa.z = EXP2(dts * A2[s + 2]); pa.w = EXP2(dts * A2[s + 3]);
        pb.x = h[s + 0]; pb.y = h[s + 1]; pb.z = h[s + 2]; pb.w = h[s + 3];
        *(float4*)&chA[base + s] = pa;
        *(float4*)&chB[base + s] = pb;
    }
}

// ---- scan2p: hierarchical parallel inter-chunk scan ----
__global__ __launch_bounds__(256) void scan2p(const float* __restrict__ chA,
                                              const float* __restrict__ chB,
                                              float* __restrict__ hst) {
    int tid = threadIdx.x;
    int ll = tid & 15;
    int g  = tid >> 4;
    int lane = blockIdx.x * 16 + ll;
    float a[16], b[16];
    #pragma unroll
    for (int i = 0; i < 16; ++i) {
        int c = g * 16 + i;
        a[i] = chA[(size_t)c * NLANE + lane];
        b[i] = chB[(size_t)c * NLANE + lane];
    }
    float Ath = 1.f, Bth = 0.f;
    #pragma unroll
    for (int i = 0; i < 16; ++i) {
        Bth = fmaf(a[i], Bth, b[i]);
        Ath *= a[i];
    }
    __shared__ float sA[16][17], sB[16][17];
    sA[g][ll] = Ath; sB[g][ll] = Bth;
    __syncthreads();
    #pragma unroll
    for (int step = 1; step < 16; step <<= 1) {
        float pA = 1.f, pB = 0.f;
        if (g >= step) { pA = sA[g - step][ll]; pB = sB[g - step][ll]; }
        __syncthreads();
        if (g >= step) {
            float cA = sA[g][ll], cB = sB[g][ll];
            sA[g][ll] = cA * pA;
            sB[g][ll] = fmaf(cA, pB, cB);
        }
        __syncthreads();
    }
    float h = (g == 0) ? 0.f : sB[g - 1][ll];
    #pragma unroll
    for (int i = 0; i < 16; ++i) {
        int c = g * 16 + i;
        hst[(size_t)c * NLANE + lane] = h;
        h = fmaf(a[i], h, b[i]);
    }
}

// ---- scan3fix: elementwise fix-up + gate. block 256 = 16 l x 16 d; grid (24, NCH) ----
__global__ __launch_bounds__(256) void scan3fix(const float* __restrict__ hst,
                                                const float* __restrict__ Dloc,
                                                const float* __restrict__ x_dbl,
                                                const float* __restrict__ A2pre,
                                                const unsigned short* __restrict__ xsb,
                                                const float* __restrict__ xz,
                                                const float* __restrict__ Dvec,
                                                unsigned short* __restrict__ ybuf) {
    int dg = blockIdx.x;
    int c  = blockIdx.y;
    int tid = threadIdx.x;
    int ll = tid >> 4, dl = tid & 15;
    int d = dg * 16 + dl;
    int l = c * 16 + ll;
    __shared__ float hpS[16][17];
    __shared__ float A2S[16][17];
    __shared__ float CsS[256];
    {
        int dd = tid >> 4, ss = tid & 15;
        hpS[dd][ss] = hst[(size_t)c * NLANE + dg * 256 + tid];
        A2S[dd][ss] = A2pre[(size_t)dg * 256 + tid];
        CsS[tid]    = x_dbl[(size_t)(c * 16 + dd) * 64 + 28 + ss];
    }
    __syncthreads();
    float Dl = Dloc[(size_t)l * DI + d];
    float y  = bf2f(ybuf[(size_t)l * DI + d]);
    float xv = bf2f(xsb[(size_t)l * DI + d]);
    float z  = xz[(size_t)l * 768 + 384 + d];
    #pragma unroll
    for (int s = 0; s < 16; ++s) {
        float e = EXP2(A2S[dl][s] * Dl);
        y = fmaf(CsS[ll * 16 + s] * e, hpS[dl][s], y);
    }
    float val = (y + xv * Dvec[d]) * siluf_(z);
    ybuf[(size_t)l * DI + d] = f2bf(val);
}

// ---- gemmln: gout = ybuf @ W_out^T (64x192 tile, full N) + residual + LN2 -> o5 ----
// grid 64 blocks x 256 threads
__global__ __launch_bounds__(256) void gemmln(const unsigned short* __restrict__ A,
                                              const unsigned short* __restrict__ Wb,
                                              const float* __restrict__ tokens,
                                              const float* __restrict__ g,
                                              const float* __restrict__ bb,
                                              float* __restrict__ o5) {
    constexpr int K = 384, KT = 192, KP = KT + 8;
    __shared__ char smem[(64 + 192) * KP * 2];     // 102.4 KB, reused for P
    unsigned short* As = (unsigned short*)smem;
    unsigned short* Bs = As + 64 * KP;
    float* P = (float*)smem;                       // [64][193] after MFMA
    __shared__ float ms[64], rs[64];
    int bm = blockIdx.x * 64;
    int tid = threadIdx.x;
    int lane = tid & 63, w = tid >> 6;
    int r16 = lane & 15, hh = lane >> 4;
    f32x4 acc[12] = {};
    for (int kt = 0; kt < K; kt += KT) {
        for (int cc = tid; cc < 64 * (KT / 8); cc += 256) {
            int row = cc / (KT / 8), col = (cc % (KT / 8)) * 8;
            *(u16x8*)&As[row * KP + col] = *(const u16x8*)(A + (size_t)(bm + row) * K + kt + col);
        }
        for (int cc = tid; cc < 192 * (KT / 8); cc += 256) {
            int row = cc / (KT / 8), col = (cc % (KT / 8)) * 8;
            *(u16x8*)&Bs[row * KP + col] = *(const u16x8*)(Wb + (size_t)row * K + kt + col);
        }
        __syncthreads();
        #pragma unroll
        for (int k0 = 0; k0 < KT; k0 += 32) {
            bf16x8 a = *(const bf16x8*)&As[(w * 16 + r16) * KP + k0 + 8 * hh];
            #pragma unroll
            for (int j = 0; j < 12; ++j) {
                bf16x8 b = *(const bf16x8*)&Bs[(j * 16 + r16) * KP + k0 + 8 * hh];
                acc[j] = __builtin_amdgcn_mfma_f32_16x16x32_bf16(a, b, acc[j], 0, 0, 0);
            }
        }
        __syncthreads();
    }
    // P = tokens tile (residual)
    for (int e = tid; e < 64 * 192; e += 256) {
        int row = e / 192, col = e - row * 192;
        P[row * 193 + col] = tokens[(size_t)(bm + row) * DIMC + col];
    }
    __syncthreads();
    // += gout (each element owned by exactly one lane)
    #pragma unroll
    for (int j = 0; j < 12; ++j)
        #pragma unroll
        for (int i = 0; i < 4; ++i)
            P[(w * 16 + hh * 4 + i) * 193 + j * 16 + r16] += acc[j][i];
    __syncthreads();
    // LN stats: 4 threads per token
    {
        int tk = tid >> 2, q = tid & 3;
        float s1 = 0.f, s2 = 0.f;
        #pragma unroll
        for (int u = 0; u < 48; ++u) {
            float v = P[tk * 193 + q * 48 + u];
            s1 += v; s2 += v * v;
        }
        s1 += __shfl_xor(s1, 1); s2 += __shfl_xor(s2, 1);
        s1 += __shfl_xor(s1, 2); s2 += __shfl_xor(s2, 2);
        if (q == 0) {
            float m = s1 * (1.f / 192.f);
            ms[tk] = m;
            rs[tk] = rsqrtf(s2 * (1.f / 192.f) - m * m + 1e-5f);
        }
    }
    __syncthreads();
    // write o5 transposed: rows bm..bm+63 share t
    int t = bm >> 8;
    int sp0 = bm & 255;
    for (int e = tid; e < 64 * 192; e += 256) {
        int cch = e >> 6, row = e & 63;
        float val = (P[row * 193 + cch] - ms[row]) * rs[row] * g[cch] + bb[cch];
        o5[(size_t)cch * 4096 + t * 256 + sp0 + row] = val;
    }
}

// ---- upfft: per (c,t) block — recompute channel weight (pooled DFT) + upsample ----
__global__ __launch_bounds__(256) void upfft(const float* __restrict__ o5,
                                             const float* __restrict__ x,
                                             float* __restrict__ out) {
    int blk = blockIdx.x;          // c*16 + t
    int c = blk >> 4, t = blk & 15;
    int tid = threadIdx.x;
    __shared__ float pl[256];
    __shared__ float pooled[16];
    __shared__ float mag[8];
    __shared__ float wgt_s;
    int wv = tid >> 6, lane = tid & 63;
    #pragma unroll
    for (int rr = 0; rr < 4; ++rr) {
        int r = wv * 4 + rr;
        float s = 0.f;
        #pragma unroll
        for (int u = 0; u < 4; ++u) {
            float v = o5[(size_t)c * 4096 + r * 256 + lane + u * 64];
            s += v;
            if (r == t) pl[lane + u * 64] = v;
        }
        s += __shfl_xor(s, 1); s += __shfl_xor(s, 2); s += __shfl_xor(s, 4);
        s += __shfl_xor(s, 8); s += __shfl_xor(s, 16); s += __shfl_xor(s, 32);
        if (lane == 0) pooled[r] = s * (1.f / 256.f);
    }
    __syncthreads();
    if (tid >= 1 && tid <= 7) {
        int k = tid;
        float re = 0.f, im = 0.f;
        for (int tt = 0; tt < 16; ++tt) {
            float ang = -0.39269908169872414f * (float)(k * tt);
            re = fmaf(pooled[tt], cosf(ang), re);
            im = fmaf(pooled[tt], sinf(ang), im);
        }
        mag[k] = sqrtf(re * re + im * im);
    }
    __syncthreads();
    if (tid == 0) {
        float m = 0.f;
        for (int k = 1; k <= 7; ++k) m += mag[k];
        wgt_s = sigmoidf_(m * (1.f / 7.f));
    }
    __syncthreads();
    float wc = wgt_s;
    size_t planeoff = (size_t)blk * 4096;
    #pragma unroll
    for (int p = 0; p < 4; ++p) {
        int px4 = p * 256 + tid;       // w-quad index 0..1023
        int k = px4 & 15;
        int hrow = px4 >> 4;           // 0..63
        float sh = hrow * 0.25f - 0.375f;
        int h0 = (int)floorf(sh); float fh = sh - (float)h0;
        int h0c = min(max(h0, 0), 15), h1c = min(max(h0 + 1, 0), 15);
        int cm = max(k - 1, 0), cp = min(k + 1, 15);
        float r0m = pl[h0c * 16 + cm], r00 = pl[h0c * 16 + k], r0p = pl[h0c * 16 + cp];
        float r1m = pl[h1c * 16 + cm], r10 = pl[h1c * 16 + k], r1p = pl[h1c * 16 + cp];
        float gh = 1.f - fh;
        float vm = r0m * gh + r1m * fh;
        float v0 = r00 * gh + r10 * fh;
        float vp = r0p * gh + r1p * fh;
        size_t off = planeoff + (size_t)px4 * 4;
        float4 xv = *(const float4*)(x + off);
        float4 o;
        o.x = (vm * 0.375f + v0 * 0.625f) * wc * sigmoidf_(xv.x);
        o.y = (vm * 0.125f + v0 * 0.875f) * wc * sigmoidf_(xv.y);
        o.z = (v0 * 0.875f + vp * 0.125f) * wc * sigmoidf_(xv.z);
        o.w = (v0 * 0.625f + vp * 0.375f) * wc * sigmoidf_(xv.w);
        *(float4*)(out + off) = o;
    }
}

extern "C" void kernel_launch(void* const* d_in, const int* in_sizes, int n_in,
                              void* d_out, int out_size, void* d_ws, size_t ws_size,
                              hipStream_t stream) {
    const float* x      = (const float*)d_in[0];
    const float* ln1_g  = (const float*)d_in[1];
    const float* ln1_b  = (const float*)d_in[2];
    const float* ln2_g  = (const float*)d_in[3];
    const float* ln2_b  = (const float*)d_in[4];
    const float* W_in   = (const float*)d_in[5];
    const float* conv_w = (const float*)d_in[6];
    const float* conv_b = (const float*)d_in[7];
    const float* W_xp   = (const float*)d_in[8];
    const float* W_dt   = (const float*)d_in[9];
    const float* b_dt   = (const float*)d_in[10];
    const float* A_log  = (const float*)d_in[11];
    const float* Dvec   = (const float*)d_in[12];
    const float* W_out  = (const float*)d_in[13];
    float* out = (float*)d_out;

    float* ws = (float*)d_ws;
    float* tokens = ws;  ws += (size_t)LTOK * DIMC;
    float* xz     = ws;  ws += (size_t)LTOK * 768;
    float* x_dbl  = ws;  ws += (size_t)LTOK * 64;
    float* chA    = ws;  ws += (size_t)NLANE * NCH;
    float* chB    = ws;  ws += (size_t)NLANE * NCH;
    float* hst    = ws;  ws += (size_t)NLANE * NCH;
    float* Dloc   = ws;  ws += (size_t)LTOK * DI;
    float* o5     = ws;  ws += (size_t)DIMC * LTOK;
    float* A2pre  = ws;  ws += NLANE;
    unsigned short* ytok     = (unsigned short*)ws;  ws += (size_t)LTOK * DIMC / 2;
    unsigned short* ybuf     = (unsigned short*)ws;  ws += (size_t)LTOK * DI / 2;
    unsigned short* xsb      = (unsigned short*)ws;  ws += (size_t)LTOK * DI / 2;
    unsigned short* W_in_bf  = (unsigned short*)ws;  ws += (size_t)768 * 192 / 2;
    unsigned short* W_out_bf = (unsigned short*)ws;  ws += (size_t)192 * 384 / 2;
    unsigned short* W_xp_pad = (unsigned short*)ws;  ws += (size_t)64 * 384 / 2;

    poolln_kernel<<<288, 256, 0, stream>>>(x, ln1_g, ln1_b, W_in, W_out, W_xp, A_log,
                                           tokens, ytok, W_in_bf, W_out_bf, W_xp_pad, A2pre);
    gemm_mfma<192><<<dim3(12, 64), 256, 0, stream>>>(ytok, W_in_bf, xz, 768);
    convscan<<<NCH, 384, 0, stream>>>(xz, conv_w, conv_b, W_xp_pad, W_dt, b_dt, A2pre,
                                      xsb, x_dbl, chA, chB, Dloc, ybuf);
    scan2p<<<NLANE / 16, 256, 0, stream>>>(chA, chB, hst);
    scan3fix<<<dim3(24, NCH), 256, 0, stream>>>(hst, Dloc, x_dbl, A2pre, xsb, xz, Dvec, ybuf);
    gemmln<<<64, 256, 0, stream>>>(ybuf, W_out_bf, tokens, ln2_g, ln2_b, o5);
    upfft<<<3072, 256, 0, stream>>>(o5, x, out);
}